// Round 15
// baseline (128.796 us; speedup 1.0000x reference)
//
#include <hip/hip_runtime.h>
#include <math.h>

#define B_    8
#define T_    2000
#define H_    256
#define FOUT_ 257
#define ALEN_ 128

typedef __attribute__((ext_vector_type(8))) short bf16x8;
typedef __attribute__((ext_vector_type(4))) float f32x4;
typedef __attribute__((ext_vector_type(16))) float f32x16;
typedef __attribute__((ext_vector_type(8))) unsigned short u16x8;

// ---------------------------------------------------------------------------
// truncation split: x = hi + lo exactly at f32
__device__ __forceinline__ void split1(float x, unsigned short& h, unsigned short& l) {
    unsigned u = __builtin_bit_cast(unsigned, x);
    h = (unsigned short)(u >> 16);
    float hf = __builtin_bit_cast(float, u & 0xFFFF0000u);
    l = (unsigned short)(__builtin_bit_cast(unsigned, x - hf) >> 16);
}
__device__ __forceinline__ void split8(float4 f0, float4 f1, bf16x8& h, bf16x8& l) {
    float f[8] = {f0.x, f0.y, f0.z, f0.w, f1.x, f1.y, f1.z, f1.w};
#pragma unroll
    for (int i = 0; i < 8; ++i) {
        unsigned short hh, ll;
        split1(f[i], hh, ll);
        h[i] = (short)hh; l[i] = (short)ll;
    }
}
__device__ __forceinline__ void gld16(const void* g, void* l) {
    __builtin_amdgcn_global_load_lds(
        (const __attribute__((address_space(1))) unsigned*)g,
        (__attribute__((address_space(3))) unsigned*)l, 16, 0, 0);
}

// ---------------------------------------------------------------------------
// prep:
//  [0,2000):    qsplit  q -> q2h/q2l
//  [2000,3008): k -> kh/kl (row-major split) + ktn (PV-frag-ordered bf16-hi)
//  [3008,3264): W_score -> wsn frag-ordered (attn phase0 B)
//  [3264,3776): W_enh -> wen frag-ordered for streaming-B GEMM:
//               wen[kt(16)][nq(8)][kc(2)][lh(2)][lm(32)][e(8)],
//               elem = We[nq*32+lm][kt*32 + kc*16 + lh*8 + e]
//  [3776,4288): W_mask -> wmn frag-ordered (stage-2 B); rows 257..319 zero.
__global__ __launch_bounds__(256) void prep(
    const float* __restrict__ k, const float* __restrict__ q,
    const float* __restrict__ Ws, const float* __restrict__ We,
    const float* __restrict__ Wm,
    unsigned short* __restrict__ q2h, unsigned short* __restrict__ q2l,
    unsigned short* __restrict__ kh, unsigned short* __restrict__ kl,
    unsigned short* __restrict__ ktn,
    unsigned short* __restrict__ wsnh, unsigned short* __restrict__ wsnl,
    unsigned short* __restrict__ wenh, unsigned short* __restrict__ wenl,
    unsigned short* __restrict__ wmnh, unsigned short* __restrict__ wmnl)
{
    __shared__ float tile[16][260];
    const int bx = blockIdx.x, tid = threadIdx.x;

    if (bx < 2000) {                     // ---- qsplit
        const size_t i = ((size_t)bx * 256 + tid) * 8;
        const float4 f0 = *(const float4*)(q + i);
        const float4 f1 = *(const float4*)(q + i + 4);
        bf16x8 h, l;
        split8(f0, f1, h, l);
        *(bf16x8*)(q2h + i) = h;
        *(bf16x8*)(q2l + i) = l;
    } else if (bx < 3008) {              // ---- k prep
        const int bid = bx - 2000;
        const int b = bid / 126;
        const int g = bid % 126;
        const int s0 = g * 16;
        const int r = tid >> 4, cs = (tid & 15) * 16;
        const int s = s0 + r;
        if (s < T_) {
            const size_t ko = ((size_t)b * T_ + s) * H_ + cs;
            const float* src = k + ko;
#pragma unroll
            for (int i = 0; i < 2; ++i) {
                const float4 v0 = *(const float4*)(src + i * 8);
                const float4 v1 = *(const float4*)(src + i * 8 + 4);
                bf16x8 h, l;
                split8(v0, v1, h, l);
                *(bf16x8*)(kh + ko + i * 8) = h;
                *(bf16x8*)(kl + ko + i * 8) = l;
                const float ff[8] = {v0.x, v0.y, v0.z, v0.w, v1.x, v1.y, v1.z, v1.w};
#pragma unroll
                for (int j = 0; j < 8; ++j) tile[r][cs + i * 8 + j] = ff[j];
            }
        } else {
#pragma unroll
            for (int i = 0; i < 16; ++i) tile[r][cs + i] = 0.f;
        }
        __syncthreads();
        const int h = tid;
        const int ht = h >> 4, lq = h & 15;
        u16x8 o0, o1;
#pragma unroll
        for (int ss = 0; ss < 8; ++ss)
            o0[ss] = (unsigned short)(__builtin_bit_cast(unsigned, tile[ss][h]) >> 16);
#pragma unroll
        for (int ss = 0; ss < 8; ++ss)
            o1[ss] = (unsigned short)(__builtin_bit_cast(unsigned, tile[ss + 8][h]) >> 16);
        unsigned short* dst = ktn + (((size_t)(b * 16 + ht) * 126) + g) * 256 + lq * 8;
        *(u16x8*)(dst) = o0;
        *(u16x8*)(dst + 128) = o1;
    } else if (bx < 3264) {              // ---- W_score -> wsn
        const int g = bx - 3008;
        const int hcol = tid;
        unsigned short h, l; split1(Ws[g * 256 + hcol], h, l);
        const int ht = g >> 4, lq = g & 15;
        const int kg = hcol >> 5, lk = (hcol >> 3) & 3, e = hcol & 7;
        const int off = ((ht * 8 + kg) * 64 + lk * 16 + lq) * 8 + e;
        wsnh[off] = h; wsnl[off] = l;
    } else if (bx < 3776) {              // ---- W_enh -> wen frag-ordered
        const int idx = (bx - 3264) * 256 + tid;  // 0..131071
        const int n = idx >> 9;           // 0..255 (enh col)
        const int kk = idx & 511;         // 0..511
        unsigned short h, l; split1(We[idx], h, l);
        const int kt = kk >> 5, kc = (kk >> 4) & 1, lh2 = (kk >> 3) & 1, e = kk & 7;
        const int nq = n >> 5, lm2 = n & 31;
        const int off = ((((kt * 8 + nq) * 2 + kc) * 2 + lh2) * 32 + lm2) * 8 + e;
        wenh[off] = h; wenl[off] = l;
    } else {                             // ---- W_mask -> wmn (rows < 320)
        const int r2 = bx - 3776;        // row (out col) 0..511
        if (r2 < 320) {
            const float x = (r2 < FOUT_) ? Wm[r2 * 256 + tid] : 0.f;
            unsigned short h, l; split1(x, h, l);
            const int nt = r2 >> 5, lm2 = r2 & 31;
            const int f = tid >> 4, hh2 = (tid >> 3) & 1, e = tid & 7;
            const int off = (((nt * 16 + f) * 2 + hh2) * 32 + lm2) * 8 + e;
            wmnh[off] = h; wmnl[off] = l;
        }
    }
}

// ---------------------------------------------------------------------------
// Fused banded attention (R11-proven, unchanged).
__global__ __launch_bounds__(256) void band_attn_mfma(
    const unsigned short* __restrict__ q2h, const unsigned short* __restrict__ q2l,
    const unsigned short* __restrict__ wsnh, const unsigned short* __restrict__ wsnl,
    const unsigned short* __restrict__ kh, const unsigned short* __restrict__ kl,
    const unsigned short* __restrict__ ktn,
    unsigned short* __restrict__ Ch, unsigned short* __restrict__ Cl)
{
    __shared__ float S[16][164];
    __shared__ unsigned short PH[16][168];
    __shared__ unsigned short PL[16][168];
    __shared__ unsigned short QSH[16 * 256];
    __shared__ unsigned short QSL[16 * 256];

    const int bid = blockIdx.x;
    const int b = bid & 7;
    const int t0 = (bid >> 3) * 16;
    const int tid = threadIdx.x;
    const int w = tid >> 6, l = tid & 63;
    const int lq = l & 15;
    const int lk = l >> 4;
    const int s_lo = max(0, t0 - ALEN_);
    const size_t qrow = (size_t)b * T_ + t0;
    const size_t kb = (size_t)b * T_ * H_;

    // ---- phase 0: qs tile = q2[16 rows] @ Ws^T (3-term), D -> LDS ----
    {
        bf16x8 aH[8], aL[8];
#pragma unroll
        for (int kg = 0; kg < 8; ++kg) {
            const size_t o = (qrow + lq) * H_ + kg * 32 + lk * 8;
            aH[kg] = *(const bf16x8*)(q2h + o);
            aL[kg] = *(const bf16x8*)(q2l + o);
        }
        for (int ht = w; ht < 16; ht += 4) {
            f32x4 acc = {};
#pragma unroll
            for (int kg = 0; kg < 8; ++kg) {
                const int fo = ((ht * 8 + kg) * 64 + lk * 16 + lq) * 8;
                const bf16x8 bh = *(const bf16x8*)(wsnh + fo);
                const bf16x8 bl = *(const bf16x8*)(wsnl + fo);
                acc = __builtin_amdgcn_mfma_f32_16x16x32_bf16(aH[kg], bh, acc, 0, 0, 0);
                acc = __builtin_amdgcn_mfma_f32_16x16x32_bf16(aH[kg], bl, acc, 0, 0, 0);
                acc = __builtin_amdgcn_mfma_f32_16x16x32_bf16(aL[kg], bh, acc, 0, 0, 0);
            }
#pragma unroll
            for (int r = 0; r < 4; ++r) {
                unsigned short h2, l2;
                split1(acc[r], h2, l2);
                const int t = lk * 4 + r;
                unsigned off = (unsigned)(t * 512 + (ht * 16 + lq) * 2);
                off ^= (unsigned)((t & 7) << 4);
                *(unsigned short*)((char*)QSH + off) = h2;
                *(unsigned short*)((char*)QSL + off) = l2;
            }
        }
    }
    __syncthreads();

    // ---- QK^T ----
    bf16x8 aH[8], aL[8];
#pragma unroll
    for (int hc = 0; hc < 8; ++hc) {
        unsigned off = (unsigned)(lq * 512 + hc * 64 + lk * 16);
        off ^= (unsigned)((lq & 7) << 4);
        aH[hc] = *(const bf16x8*)((const char*)QSH + off);
        aL[hc] = *(const bf16x8*)((const char*)QSL + off);
    }
    for (int st = w; st < 9; st += 4) {
        f32x4 acc = {};
        const int s = s_lo + st * 16 + lq;
        const size_t ro = kb + (size_t)s * H_ + lk * 8;
#pragma unroll
        for (int hc = 0; hc < 8; ++hc) {
            const bf16x8 bh = *(const bf16x8*)(kh + ro + hc * 32);
            const bf16x8 bl = *(const bf16x8*)(kl + ro + hc * 32);
            acc = __builtin_amdgcn_mfma_f32_16x16x32_bf16(aH[hc], bh, acc, 0, 0, 0);
            acc = __builtin_amdgcn_mfma_f32_16x16x32_bf16(aH[hc], bl, acc, 0, 0, 0);
            acc = __builtin_amdgcn_mfma_f32_16x16x32_bf16(aL[hc], bh, acc, 0, 0, 0);
        }
#pragma unroll
        for (int r = 0; r < 4; ++r)
            S[lk * 4 + r][st * 16 + lq] = acc[r];
    }
    __syncthreads();

    // ---- softmax (band-masked, P pre-scaled by 1/denom) ----
    {
        const int q = tid >> 4, li = tid & 15;
        const int t = t0 + q;
        const int jlo = max(0, t - ALEN_) - s_lo;
        const int jhi = t - s_lo;
        float m = -INFINITY;
#pragma unroll
        for (int j = 0; j < 10; ++j) {
            const int s = li + j * 16;
            if (s >= jlo && s <= jhi) m = fmaxf(m, S[q][s]);
        }
#pragma unroll
        for (int off = 8; off; off >>= 1) m = fmaxf(m, __shfl_xor(m, off));
        float sum = 0.f;
#pragma unroll
        for (int j = 0; j < 10; ++j) {
            const int s = li + j * 16;
            const float e = (s >= jlo && s <= jhi) ? expf(S[q][s] - m) : 0.f;
            S[q][s] = e;
            sum += e;
        }
#pragma unroll
        for (int off = 8; off; off >>= 1) sum += __shfl_xor(sum, off);
        const float inv = 1.f / (sum + 1e-30f);
#pragma unroll
        for (int j = 0; j < 10; ++j) {
            const int s = li + j * 16;
            unsigned short hh2, ll2;
            split1(S[q][s] * inv, hh2, ll2);
            PH[q][s] = hh2;
            PL[q][s] = ll2;
        }
    }
    __syncthreads();

    // ---- PV (frag-ordered ktn) ----
    const int gbase = s_lo >> 4;
    for (int ht = w; ht < 16; ht += 4) {
        f32x4 acc = {};
        const unsigned short* ktb = ktn + ((size_t)(b * 16 + ht) * 126) * 256;
#pragma unroll
        for (int sc = 0; sc < 5; ++sc) {
            const bf16x8 ph = *(const bf16x8*)((const char*)&PH[lq][0] + sc * 64 + lk * 16);
            const bf16x8 pl = *(const bf16x8*)((const char*)&PL[lq][0] + sc * 64 + lk * 16);
            const bf16x8 bt = *(const bf16x8*)(
                ktb + (size_t)(gbase + 2 * sc + (lk >> 1)) * 256 + (lk & 1) * 128 + lq * 8);
            acc = __builtin_amdgcn_mfma_f32_16x16x32_bf16(ph, bt, acc, 0, 0, 0);
            acc = __builtin_amdgcn_mfma_f32_16x16x32_bf16(pl, bt, acc, 0, 0, 0);
        }
#pragma unroll
        for (int r = 0; r < 4; ++r) {
            unsigned short hh2, ll2;
            split1(acc[r], hh2, ll2);
            const size_t o = (qrow + lk * 4 + r) * H_ + ht * 16 + lq;
            Ch[o] = hh2;
            Cl[o] = ll2;
        }
    }
}

// ---------------------------------------------------------------------------
// Fused enh+out GEMM v5 (A-resident / B-streaming):
//   - A panel (32 rows x 512 K, hi/lo) loaded ONCE into 64KB LDS (1 barrier).
//   - K-loop has ZERO barriers: B-frags stream from frag-ordered wen (global,
//     L2-resident, 1KB wave-contiguous) straight into MFMA; compiler pipelines
//     the fully-unrolled load/MFMA stream; waves drift freely.
//   - Stage 2 (out GEMM from LDS EH/EL x wmn) unchanged; EH/EL alias A region.
// Arithmetic & K-order identical to R11-R14.
__global__ __launch_bounds__(256) void gemm_enh_out(
    const unsigned short* __restrict__ Ah1, const unsigned short* __restrict__ Al1,
    const unsigned short* __restrict__ Ah2, const unsigned short* __restrict__ Al2,
    const unsigned short* __restrict__ wenh, const unsigned short* __restrict__ wenl,
    const float* __restrict__ b_enh,
    const unsigned short* __restrict__ wmnh, const unsigned short* __restrict__ wmnl,
    const float* __restrict__ b_mask, float* __restrict__ out)
{
    __shared__ char LDSB[64 * 1024];
    // A: AH @0 (32KB: row r at r*1024B, 512 k-elems), AL @32768.
    // swizzle: byte-off within row ^= (row&7)<<4 (16B granule, involution).
    // after main loop: EH @0 (16KB: 32x512B), EL @16384.

    const int tid = threadIdx.x;
    const int m0 = blockIdx.x * 32;
    const int w = tid >> 6, l = tid & 63;
    const int lm = l & 31, hh = l >> 5;

    // ---- load A panel once (16 gld16/thread, inverse-swizzled source) ----
#pragma unroll
    for (int p = 0; p < 16; ++p) {
        const unsigned D = p * 4096u + (unsigned)tid * 16u;   // 0..65535
        const unsigned reg = D >> 15;                         // 0=hi, 1=lo
        const unsigned Dr = D & 32767u;
        const unsigned row = Dr >> 10;                        // 0..31
        const unsigned off = (Dr & 1023u) ^ ((row & 7u) << 4);
        const unsigned kelem = off >> 1;                      // 0..511
        const unsigned short* src;
        if (kelem < 256)
            src = (reg ? Al1 : Ah1) + (size_t)(m0 + row) * 256 + kelem;
        else
            src = (reg ? Al2 : Ah2) + (size_t)(m0 + row) * 256 + (kelem - 256);
        gld16(src, LDSB + p * 4096 + (size_t)w * 1024);
    }
    __syncthreads();

    // ---- barrier-free K-loop: A from LDS, B streamed from wen ----
    f32x16 acc0 = {}, acc1 = {};
    {
        const char* AH = LDSB;
        const char* AL = LDSB + 32768;
        const unsigned swa = (unsigned)((lm & 7) << 4);
#pragma unroll
        for (int kt = 0; kt < 16; ++kt) {
#pragma unroll
            for (int kc = 0; kc < 2; ++kc) {
                const unsigned ko = (unsigned)(kt * 64 + kc * 32 + hh * 16);
                const unsigned ao = (unsigned)(lm * 1024) + (ko ^ swa);
                const bf16x8 ah = *(const bf16x8*)(AH + ao);
                const bf16x8 al = *(const bf16x8*)(AL + ao);
                const size_t bo0 = ((((size_t)(kt * 8 + w * 2) * 2 + kc) * 2 + hh) * 32 + lm) * 8;
                const size_t bo1 = ((((size_t)(kt * 8 + w * 2 + 1) * 2 + kc) * 2 + hh) * 32 + lm) * 8;
                const bf16x8 bh0 = *(const bf16x8*)(wenh + bo0);
                const bf16x8 bl0 = *(const bf16x8*)(wenl + bo0);
                const bf16x8 bh1 = *(const bf16x8*)(wenh + bo1);
                const bf16x8 bl1 = *(const bf16x8*)(wenl + bo1);
                acc0 = __builtin_amdgcn_mfma_f32_32x32x16_bf16(ah, bh0, acc0, 0, 0, 0);
                acc0 = __builtin_amdgcn_mfma_f32_32x32x16_bf16(ah, bl0, acc0, 0, 0, 0);
                acc0 = __builtin_amdgcn_mfma_f32_32x32x16_bf16(al, bh0, acc0, 0, 0, 0);
                acc1 = __builtin_amdgcn_mfma_f32_32x32x16_bf16(ah, bh1, acc1, 0, 0, 0);
                acc1 = __builtin_amdgcn_mfma_f32_32x32x16_bf16(ah, bl1, acc1, 0, 0, 0);
                acc1 = __builtin_amdgcn_mfma_f32_32x32x16_bf16(al, bh1, acc1, 0, 0, 0);
            }
        }
    }
    __syncthreads();   // all waves done reading A before EH/EL overwrite

    // enh tile -> LDS (split, swizzled). D: col=lane&31, row=(e&3)+8*(e>>2)+4*hh
    {
        char* EH = LDSB;
        char* EL = LDSB + 16384;
#pragma unroll
        for (int ct = 0; ct < 2; ++ct) {
            const f32x16 r = ct ? acc1 : acc0;
            const int col = w * 64 + ct * 32 + lm;       // 0..255
            const float bv = b_enh[col];
#pragma unroll
            for (int e = 0; e < 16; ++e) {
                const int row = (e & 3) + 8 * (e >> 2) + 4 * hh;   // 0..31
                unsigned short h2, l2;
                split1(tanhf(r[e] + bv), h2, l2);
                unsigned off = (unsigned)(row * 512 + col * 2);
                off ^= (unsigned)((row & 7) << 4);
                *(unsigned short*)(EH + off) = h2;
                *(unsigned short*)(EL + off) = l2;
            }
        }
    }
    __syncthreads();

    // out = sigmoid(enh @ Wm^T + bm); wave w: nt = w, w+4, w+8 (w<2)
    for (int nt = w; nt < 10; nt += 4) {
        const char* EH = LDSB;
        const char* EL = LDSB + 16384;
        f32x16 o = {};
        const unsigned sw = (unsigned)((lm & 7) << 4);
#pragma unroll
        for (int f = 0; f < 16; ++f) {
            const unsigned offA = (unsigned)(lm * 512 + f * 32 + hh * 16);
            const bf16x8 ah = *(const bf16x8*)(EH + (offA ^ sw));
            const bf16x8 al = *(const bf16x8*)(EL + (offA ^ sw));
            const size_t bo = (((size_t)(nt * 16 + f) * 2 + hh) * 32 + lm) * 8;
            const bf16x8 bh = *(const bf16x8*)(wmnh + bo);
            const bf16x8 bl = *(const bf16x8*)(wmnl + bo);
            o = __builtin_amdgcn_mfma_f32_32x32x16_bf16(ah, bh, o, 0, 0, 0);
            o = __builtin_amdgcn_mfma_f32_32x32x16_bf16(ah, bl, o, 0, 0, 0);
            o = __builtin_amdgcn_mfma_f32_32x32x16_bf16(al, bh, o, 0, 0, 0);
        }
        const int gcol = nt * 32 + lm;
        if (gcol < FOUT_) {
            const float bv = b_mask[gcol];
#pragma unroll
            for (int e = 0; e < 16; ++e) {
                const int rowl = (e & 3) + 8 * (e >> 2) + 4 * hh;
                out[(size_t)(m0 + rowl) * FOUT_ + gcol] = 1.f / (1.f + expf(-(o[e] + bv)));
            }
        }
    }
}

// ---------------------------------------------------------------------------
extern "C" void kernel_launch(void* const* d_in, const int* in_sizes, int n_in,
                              void* d_out, int out_size, void* d_ws, size_t ws_size,
                              hipStream_t stream)
{
    const float* k       = (const float*)d_in[0];
    const float* q       = (const float*)d_in[1];
    const float* W_score = (const float*)d_in[2];
    const float* W_enh   = (const float*)d_in[3];
    const float* b_enh   = (const float*)d_in[4];
    const float* W_mask  = (const float*)d_in[5];
    const float* b_mask  = (const float*)d_in[6];
    float* out = (float*)d_out;

    const size_t MH = (size_t)B_ * T_ * H_;          // 4.096M elems
    unsigned short* q2h = (unsigned short*)d_ws;
    unsigned short* q2l = q2h + MH;
    unsigned short* ch  = q2l + MH;
    unsigned short* cl  = ch + MH;
    unsigned short* kh  = cl + MH;
    unsigned short* kl  = kh + MH;
    unsigned short* ktn = kl + MH;                   // 8*16*126*256
    unsigned short* wsnh = ktn + (size_t)B_ * 16 * 126 * 256;
    unsigned short* wsnl = wsnh + 65536;
    unsigned short* wenh = wsnl + 65536;
    unsigned short* wenl = wenh + 131072;
    unsigned short* wmnh = wenl + 131072;            // 320x256 frag-ordered
    unsigned short* wmnl = wmnh + 81920;

    dim3 blk(256);

    prep<<<dim3(4288), blk, 0, stream>>>(
        k, q, W_score, W_enh, W_mask,
        q2h, q2l, kh, kl, ktn, wsnh, wsnl, wenh, wenl, wmnh, wmnl);

    band_attn_mfma<<<dim3(1000), blk, 0, stream>>>(
        q2h, q2l, wsnh, wsnl, kh, kl, ktn, ch, cl);

    gemm_enh_out<<<dim3(500), blk, 0, stream>>>(
        ch, cl, q2h, q2l, wenh, wenl, b_enh, wmnh, wmnl, b_mask, out);
}

// Round 16
// 111.950 us; speedup vs baseline: 1.1505x; 1.1505x over previous
//
#include <hip/hip_runtime.h>
#include <math.h>

#define B_    8
#define T_    2000
#define H_    256
#define FOUT_ 257
#define ALEN_ 128

typedef __attribute__((ext_vector_type(8))) short bf16x8;
typedef __attribute__((ext_vector_type(4))) float f32x4;
typedef __attribute__((ext_vector_type(16))) float f32x16;
typedef __attribute__((ext_vector_type(8))) unsigned short u16x8;

// ---------------------------------------------------------------------------
// truncation split: x = hi + lo exactly at f32
__device__ __forceinline__ void split1(float x, unsigned short& h, unsigned short& l) {
    unsigned u = __builtin_bit_cast(unsigned, x);
    h = (unsigned short)(u >> 16);
    float hf = __builtin_bit_cast(float, u & 0xFFFF0000u);
    l = (unsigned short)(__builtin_bit_cast(unsigned, x - hf) >> 16);
}
__device__ __forceinline__ void split8(float4 f0, float4 f1, bf16x8& h, bf16x8& l) {
    float f[8] = {f0.x, f0.y, f0.z, f0.w, f1.x, f1.y, f1.z, f1.w};
#pragma unroll
    for (int i = 0; i < 8; ++i) {
        unsigned short hh, ll;
        split1(f[i], hh, ll);
        h[i] = (short)hh; l[i] = (short)ll;
    }
}
__device__ __forceinline__ void gld16(const void* g, void* l) {
    __builtin_amdgcn_global_load_lds(
        (const __attribute__((address_space(1))) unsigned*)g,
        (__attribute__((address_space(3))) unsigned*)l, 16, 0, 0);
}

// ---------------------------------------------------------------------------
// prep (R11-proven):
//  [0,2000):    qsplit  q -> q2h/q2l
//  [2000,3008): k -> kh/kl (row-major split) + ktn (PV-frag-ordered bf16-hi)
//  [3008,3264): W_score -> wsn frag-ordered (attn phase0 B)
//  [3264,3776): W_enh split (row-major, gemm staging)
//  [3776,4288): W_mask -> wmn frag-ordered (stage-2 B); rows 257..319 zero.
__global__ __launch_bounds__(256) void prep(
    const float* __restrict__ k, const float* __restrict__ q,
    const float* __restrict__ Ws, const float* __restrict__ We,
    const float* __restrict__ Wm,
    unsigned short* __restrict__ q2h, unsigned short* __restrict__ q2l,
    unsigned short* __restrict__ kh, unsigned short* __restrict__ kl,
    unsigned short* __restrict__ ktn,
    unsigned short* __restrict__ wsnh, unsigned short* __restrict__ wsnl,
    unsigned short* __restrict__ weh, unsigned short* __restrict__ wel,
    unsigned short* __restrict__ wmnh, unsigned short* __restrict__ wmnl)
{
    __shared__ float tile[16][260];
    const int bx = blockIdx.x, tid = threadIdx.x;

    if (bx < 2000) {                     // ---- qsplit
        const size_t i = ((size_t)bx * 256 + tid) * 8;
        const float4 f0 = *(const float4*)(q + i);
        const float4 f1 = *(const float4*)(q + i + 4);
        bf16x8 h, l;
        split8(f0, f1, h, l);
        *(bf16x8*)(q2h + i) = h;
        *(bf16x8*)(q2l + i) = l;
    } else if (bx < 3008) {              // ---- k prep
        const int bid = bx - 2000;
        const int b = bid / 126;
        const int g = bid % 126;
        const int s0 = g * 16;
        const int r = tid >> 4, cs = (tid & 15) * 16;
        const int s = s0 + r;
        if (s < T_) {
            const size_t ko = ((size_t)b * T_ + s) * H_ + cs;
            const float* src = k + ko;
#pragma unroll
            for (int i = 0; i < 2; ++i) {
                const float4 v0 = *(const float4*)(src + i * 8);
                const float4 v1 = *(const float4*)(src + i * 8 + 4);
                bf16x8 h, l;
                split8(v0, v1, h, l);
                *(bf16x8*)(kh + ko + i * 8) = h;
                *(bf16x8*)(kl + ko + i * 8) = l;
                const float ff[8] = {v0.x, v0.y, v0.z, v0.w, v1.x, v1.y, v1.z, v1.w};
#pragma unroll
                for (int j = 0; j < 8; ++j) tile[r][cs + i * 8 + j] = ff[j];
            }
        } else {
#pragma unroll
            for (int i = 0; i < 16; ++i) tile[r][cs + i] = 0.f;
        }
        __syncthreads();
        const int h = tid;
        const int ht = h >> 4, lq = h & 15;
        u16x8 o0, o1;
#pragma unroll
        for (int ss = 0; ss < 8; ++ss)
            o0[ss] = (unsigned short)(__builtin_bit_cast(unsigned, tile[ss][h]) >> 16);
#pragma unroll
        for (int ss = 0; ss < 8; ++ss)
            o1[ss] = (unsigned short)(__builtin_bit_cast(unsigned, tile[ss + 8][h]) >> 16);
        unsigned short* dst = ktn + (((size_t)(b * 16 + ht) * 126) + g) * 256 + lq * 8;
        *(u16x8*)(dst) = o0;
        *(u16x8*)(dst + 128) = o1;
    } else if (bx < 3264) {              // ---- W_score -> wsn
        const int g = bx - 3008;
        const int hcol = tid;
        unsigned short h, l; split1(Ws[g * 256 + hcol], h, l);
        const int ht = g >> 4, lq = g & 15;
        const int kg = hcol >> 5, lk = (hcol >> 3) & 3, e = hcol & 7;
        const int off = ((ht * 8 + kg) * 64 + lk * 16 + lq) * 8 + e;
        wsnh[off] = h; wsnl[off] = l;
    } else if (bx < 3776) {              // ---- W_enh (row-major split)
        const int idx = (bx - 3264) * 256 + tid;
        unsigned short h, l; split1(We[idx], h, l);
        weh[idx] = h; wel[idx] = l;
    } else {                             // ---- W_mask -> wmn (rows < 320)
        const int r2 = bx - 3776;        // row (out col) 0..511
        if (r2 < 320) {
            const float x = (r2 < FOUT_) ? Wm[r2 * 256 + tid] : 0.f;
            unsigned short h, l; split1(x, h, l);
            const int nt = r2 >> 5, lm2 = r2 & 31;
            const int f = tid >> 4, hh2 = (tid >> 3) & 1, e = tid & 7;
            const int off = (((nt * 16 + f) * 2 + hh2) * 32 + lm2) * 8 + e;
            wmnh[off] = h; wmnl[off] = l;
        }
    }
}

// ---------------------------------------------------------------------------
// Fused banded attention v6: 32-query blocks, 512 thr (8 waves).
// Wave w: sub = w&1 (16-q sub-tile), wp = w>>2... wp = w>>1 (quarter).
// Grid 504 = 63 t-tiles x 8 batches (b = bid&7, XCD-local).
// Halves block count (serial-phase convoys), doubles per-block TLP.
// Last tile (t0=1984): rows >= 2000 read adjacent ws arrays (defined),
// garbage confined to its own MFMA rows; c-store guarded by trow < T.
__global__ __launch_bounds__(512) void band_attn_mfma(
    const unsigned short* __restrict__ q2h, const unsigned short* __restrict__ q2l,
    const unsigned short* __restrict__ wsnh, const unsigned short* __restrict__ wsnl,
    const unsigned short* __restrict__ kh, const unsigned short* __restrict__ kl,
    const unsigned short* __restrict__ ktn,
    unsigned short* __restrict__ Ch, unsigned short* __restrict__ Cl)
{
    __shared__ float S[32][164];
    __shared__ unsigned short PH[32][168];
    __shared__ unsigned short PL[32][168];
    __shared__ unsigned short QSH[32 * 256];
    __shared__ unsigned short QSL[32 * 256];

    const int bid = blockIdx.x;
    const int b = bid & 7;
    const int t0 = (bid >> 3) * 32;
    const int tid = threadIdx.x;
    const int w = tid >> 6, l = tid & 63;
    const int sub = w & 1;          // 16-row sub-tile
    const int wp = w >> 1;          // quarter 0..3
    const int lq = l & 15;
    const int lk = l >> 4;
    const int s_lo = max(0, t0 - ALEN_);
    const size_t qrow = (size_t)b * T_ + t0;
    const size_t kb = (size_t)b * T_ * H_;
    const int srow = sub * 16;      // sub-tile row base in LDS

    // ---- phase 0: qs(32 rows) = q2 @ Ws^T (3-term), D -> LDS ----
    {
        bf16x8 aH[8], aL[8];
#pragma unroll
        for (int kg = 0; kg < 8; ++kg) {
            const size_t o = (qrow + srow + lq) * H_ + kg * 32 + lk * 8;
            aH[kg] = *(const bf16x8*)(q2h + o);
            aL[kg] = *(const bf16x8*)(q2l + o);
        }
        for (int ht = wp; ht < 16; ht += 4) {
            f32x4 acc = {};
#pragma unroll
            for (int kg = 0; kg < 8; ++kg) {
                const int fo = ((ht * 8 + kg) * 64 + lk * 16 + lq) * 8;
                const bf16x8 bh = *(const bf16x8*)(wsnh + fo);
                const bf16x8 bl = *(const bf16x8*)(wsnl + fo);
                acc = __builtin_amdgcn_mfma_f32_16x16x32_bf16(aH[kg], bh, acc, 0, 0, 0);
                acc = __builtin_amdgcn_mfma_f32_16x16x32_bf16(aH[kg], bl, acc, 0, 0, 0);
                acc = __builtin_amdgcn_mfma_f32_16x16x32_bf16(aL[kg], bh, acc, 0, 0, 0);
            }
#pragma unroll
            for (int r = 0; r < 4; ++r) {
                unsigned short h2, l2;
                split1(acc[r], h2, l2);
                const int t = srow + lk * 4 + r;              // 0..31
                unsigned off = (unsigned)(t * 512 + (ht * 16 + lq) * 2);
                off ^= (unsigned)((t & 7) << 4);
                *(unsigned short*)((char*)QSH + off) = h2;
                *(unsigned short*)((char*)QSL + off) = l2;
            }
        }
    }
    __syncthreads();

    // ---- QK^T: A from LDS qs (own sub), B from kh/kl ----
    {
        bf16x8 aH[8], aL[8];
#pragma unroll
        for (int hc = 0; hc < 8; ++hc) {
            const int t = srow + lq;
            unsigned off = (unsigned)(t * 512 + hc * 64 + lk * 16);
            off ^= (unsigned)((t & 7) << 4);
            aH[hc] = *(const bf16x8*)((const char*)QSH + off);
            aL[hc] = *(const bf16x8*)((const char*)QSL + off);
        }
        for (int st = wp; st < 10; st += 4) {
            f32x4 acc = {};
            const int s = s_lo + st * 16 + lq;
            const size_t ro = kb + (size_t)s * H_ + lk * 8;
#pragma unroll
            for (int hc = 0; hc < 8; ++hc) {
                const bf16x8 bh = *(const bf16x8*)(kh + ro + hc * 32);
                const bf16x8 bl = *(const bf16x8*)(kl + ro + hc * 32);
                acc = __builtin_amdgcn_mfma_f32_16x16x32_bf16(aH[hc], bh, acc, 0, 0, 0);
                acc = __builtin_amdgcn_mfma_f32_16x16x32_bf16(aH[hc], bl, acc, 0, 0, 0);
                acc = __builtin_amdgcn_mfma_f32_16x16x32_bf16(aL[hc], bh, acc, 0, 0, 0);
            }
#pragma unroll
            for (int r = 0; r < 4; ++r)
                S[srow + lk * 4 + r][st * 16 + lq] = acc[r];
        }
    }
    __syncthreads();

    // ---- softmax (band-masked, P pre-scaled by 1/denom); 16 lanes/row ----
    {
        const int q = tid >> 4, li = tid & 15;   // q 0..31
        const int t = t0 + q;
        const int jlo = max(0, t - ALEN_) - s_lo;
        const int jhi = t - s_lo;
        float m = -INFINITY;
#pragma unroll
        for (int j = 0; j < 10; ++j) {
            const int s = li + j * 16;
            if (s >= jlo && s <= jhi) m = fmaxf(m, S[q][s]);
        }
#pragma unroll
        for (int off = 8; off; off >>= 1) m = fmaxf(m, __shfl_xor(m, off));
        float sum = 0.f;
#pragma unroll
        for (int j = 0; j < 10; ++j) {
            const int s = li + j * 16;
            const float e = (s >= jlo && s <= jhi) ? expf(S[q][s] - m) : 0.f;
            S[q][s] = e;
            sum += e;
        }
#pragma unroll
        for (int off = 8; off; off >>= 1) sum += __shfl_xor(sum, off);
        const float inv = 1.f / (sum + 1e-30f);
#pragma unroll
        for (int j = 0; j < 10; ++j) {
            const int s = li + j * 16;
            unsigned short hh2, ll2;
            split1(S[q][s] * inv, hh2, ll2);
            PH[q][s] = hh2;
            PL[q][s] = ll2;
        }
    }
    __syncthreads();

    // ---- PV (frag-ordered ktn); wave handles own sub's P rows ----
    const int gbase = s_lo >> 4;
    for (int ht = wp; ht < 16; ht += 4) {
        f32x4 acc = {};
        const unsigned short* ktb = ktn + ((size_t)(b * 16 + ht) * 126) * 256;
#pragma unroll
        for (int sc = 0; sc < 5; ++sc) {
            const bf16x8 ph = *(const bf16x8*)((const char*)&PH[srow + lq][0] + sc * 64 + lk * 16);
            const bf16x8 pl = *(const bf16x8*)((const char*)&PL[srow + lq][0] + sc * 64 + lk * 16);
            const bf16x8 bt = *(const bf16x8*)(
                ktb + (size_t)(gbase + 2 * sc + (lk >> 1)) * 256 + (lk & 1) * 128 + lq * 8);
            acc = __builtin_amdgcn_mfma_f32_16x16x32_bf16(ph, bt, acc, 0, 0, 0);
            acc = __builtin_amdgcn_mfma_f32_16x16x32_bf16(pl, bt, acc, 0, 0, 0);
        }
#pragma unroll
        for (int r = 0; r < 4; ++r) {
            const int trow = t0 + srow + lk * 4 + r;
            if (trow < T_) {
                unsigned short hh2, ll2;
                split1(acc[r], hh2, ll2);
                const size_t o = ((size_t)b * T_ + trow) * H_ + ht * 16 + lq;
                Ch[o] = hh2;
                Cl[o] = ll2;
            }
        }
    }
}

// ---------------------------------------------------------------------------
// Fused enh+out GEMM (R11-proven 55us version, verbatim): BM=64, BN=256,
// BK=32, 256 thr / 4 waves (wave tile 64x32), W staged in LDS dbuf 80KB,
// __syncthreads pipeline; stage-2 out GEMM from LDS EH/EL x wmn.
__global__ __launch_bounds__(256) void gemm_enh_out(
    const unsigned short* __restrict__ Ah1, const unsigned short* __restrict__ Al1,
    const unsigned short* __restrict__ Ah2, const unsigned short* __restrict__ Al2,
    const unsigned short* __restrict__ Wh, const unsigned short* __restrict__ Wl,
    const float* __restrict__ b_enh,
    const unsigned short* __restrict__ wmnh, const unsigned short* __restrict__ wmnl,
    const float* __restrict__ b_mask, float* __restrict__ out)
{
    __shared__ char LDSB[80 * 1024];
    // layout: AS buf0 @0, AS buf1 @8K, WS buf0 @16K, WS buf1 @48K
    // after main loop: EH @0 (32K), EL @32K (32K)

    const int tid = threadIdx.x;
    const int m0 = blockIdx.x * 64;
    const int w = tid >> 6, l = tid & 63;
    const int lm = l & 31, hh = l >> 5;
    constexpr int KB = 512, NT = 16;

    f32x16 acc00 = {}, acc01 = {}, acc10 = {}, acc11 = {};

    auto STAGEA = [&](int kt, int buf) {
        const int k0g = kt * 32;
        const unsigned short* Hs = Ah1;
        const unsigned short* Ls = Al1;
        int k0 = k0g;
        if (k0g >= 256) { Hs = Ah2; Ls = Al2; k0 = k0g - 256; }
        char* base = LDSB + buf * 8192;
#pragma unroll
        for (int p = 0; p < 2; ++p) {
            const unsigned D = p * 4096u + tid * 16u;
            const unsigned row = D >> 7;
            const unsigned u = (D & 127u) ^ ((row & 7u) << 4);
            const unsigned kelem = (u & 63u) >> 1;
            const unsigned short* src =
                ((u >> 6) ? Ls : Hs) + (size_t)(m0 + row) * 256 + k0 + kelem;
            gld16(src, base + (p * 4 + w) * 1024);
        }
    };
    auto STAGEW = [&](int kt, int buf) {
        const int k0g = kt * 32;
        char* base = LDSB + 16 * 1024 + buf * 32768;
#pragma unroll
        for (int p = 0; p < 8; ++p) {
            const unsigned D = p * 4096u + tid * 16u;
            const unsigned row = D >> 7;
            const unsigned u = (D & 127u) ^ ((row & 7u) << 4);
            const unsigned kelem = (u & 63u) >> 1;
            const unsigned short* src =
                ((u >> 6) ? Wl : Wh) + (size_t)row * KB + k0g + kelem;
            gld16(src, base + (p * 4 + w) * 1024);
        }
    };

    STAGEA(0, 0);
    STAGEW(0, 0);
    __syncthreads();

    int buf = 0;
    for (int kt = 0; kt < NT; ++kt) {
        const bool last = (kt == NT - 1);
        if (!last) { STAGEA(kt + 1, buf ^ 1); STAGEW(kt + 1, buf ^ 1); }

        const char* As = LDSB + buf * 8192;
        const char* Wsb = LDSB + 16 * 1024 + buf * 32768;
        const unsigned r_a = (unsigned)lm;
        const unsigned swa = (r_a & 7u) << 4;
        const unsigned r_b = (unsigned)(w * 64 + lm);
        const unsigned swb = (r_b & 7u) << 4;
#pragma unroll
        for (int kc = 0; kc < 2; ++kc) {
            const unsigned u = (unsigned)(kc * 32 + hh * 16);
            const bf16x8 ah0 = *(const bf16x8*)(As + r_a * 128 + (u ^ swa));
            const bf16x8 al0 = *(const bf16x8*)(As + r_a * 128 + ((u + 64) ^ swa));
            const bf16x8 ah1 = *(const bf16x8*)(As + (r_a + 32) * 128 + (u ^ swa));
            const bf16x8 al1 = *(const bf16x8*)(As + (r_a + 32) * 128 + ((u + 64) ^ swa));
            const bf16x8 bh0 = *(const bf16x8*)(Wsb + r_b * 128 + (u ^ swb));
            const bf16x8 bl0 = *(const bf16x8*)(Wsb + r_b * 128 + ((u + 64) ^ swb));
            const bf16x8 bh1 = *(const bf16x8*)(Wsb + (r_b + 32) * 128 + (u ^ swb));
            const bf16x8 bl1 = *(const bf16x8*)(Wsb + (r_b + 32) * 128 + ((u + 64) ^ swb));
            acc00 = __builtin_amdgcn_mfma_f32_32x32x16_bf16(ah0, bh0, acc00, 0, 0, 0);
            acc00 = __builtin_amdgcn_mfma_f32_32x32x16_bf16(ah0, bl0, acc00, 0, 0, 0);
            acc00 = __builtin_amdgcn_mfma_f32_32x32x16_bf16(al0, bh0, acc00, 0, 0, 0);
            acc01 = __builtin_amdgcn_mfma_f32_32x32x16_bf16(ah0, bh1, acc01, 0, 0, 0);
            acc01 = __builtin_amdgcn_mfma_f32_32x32x16_bf16(ah0, bl1, acc01, 0, 0, 0);
            acc01 = __builtin_amdgcn_mfma_f32_32x32x16_bf16(al0, bh1, acc01, 0, 0, 0);
            acc10 = __builtin_amdgcn_mfma_f32_32x32x16_bf16(ah1, bh0, acc10, 0, 0, 0);
            acc10 = __builtin_amdgcn_mfma_f32_32x32x16_bf16(ah1, bl0, acc10, 0, 0, 0);
            acc10 = __builtin_amdgcn_mfma_f32_32x32x16_bf16(al1, bh0, acc10, 0, 0, 0);
            acc11 = __builtin_amdgcn_mfma_f32_32x32x16_bf16(ah1, bh1, acc11, 0, 0, 0);
            acc11 = __builtin_amdgcn_mfma_f32_32x32x16_bf16(ah1, bl1, acc11, 0, 0, 0);
            acc11 = __builtin_amdgcn_mfma_f32_32x32x16_bf16(al1, bh1, acc11, 0, 0, 0);
        }
        __syncthreads();
        buf ^= 1;
    }

    // enh tile -> LDS (split, swizzled). D: col=lane&31, row=(e&3)+8*(e>>2)+4*hh
    {
        char* EH = LDSB;
        char* EL = LDSB + 32 * 1024;
#pragma unroll
        for (int rt = 0; rt < 2; ++rt) {
#pragma unroll
            for (int ct = 0; ct < 2; ++ct) {
                const f32x16 r = rt ? (ct ? acc11 : acc10) : (ct ? acc01 : acc00);
                const int col = w * 64 + ct * 32 + lm;   // 0..255
                const float bv = b_enh[col];
#pragma unroll
                for (int e = 0; e < 16; ++e) {
                    const int row = rt * 32 + (e & 3) + 8 * (e >> 2) + 4 * hh;
                    unsigned short h2, l2;
                    split1(tanhf(r[e] + bv), h2, l2);
                    unsigned off = (unsigned)(row * 512 + col * 2);
                    off ^= (unsigned)((row & 7) << 4);
                    *(unsigned short*)(EH + off) = h2;
                    *(unsigned short*)(EL + off) = l2;
                }
            }
        }
    }
    __syncthreads();

    // out = sigmoid(enh @ Wm^T + bm); wave w does col tiles nt = w, w+4, w+8
    for (int nt = w; nt < 10; nt += 4) {
        const char* EH = LDSB;
        const char* EL = LDSB + 32 * 1024;
        f32x16 o0 = {}, o1 = {};
#pragma unroll
        for (int f = 0; f < 16; ++f) {
            const unsigned kb2 = (unsigned)(f * 32 + hh * 16);
            const unsigned row0 = (unsigned)lm;
            const unsigned sw = (row0 & 7u) << 4;    // (row0+32)&7 == row0&7
            unsigned offA0 = row0 * 512 + kb2;
            unsigned offA1 = (row0 + 32) * 512 + kb2;
            const bf16x8 ah0 = *(const bf16x8*)(EH + (offA0 ^ sw));
            const bf16x8 al0 = *(const bf16x8*)(EL + (offA0 ^ sw));
            const bf16x8 ah1 = *(const bf16x8*)(EH + (offA1 ^ sw));
            const bf16x8 al1 = *(const bf16x8*)(EL + (offA1 ^ sw));
            const size_t bo = ((size_t)((nt * 16 + f) * 2 + hh) * 32 + lm) * 8;
            const bf16x8 bh = *(const bf16x8*)(wmnh + bo);
            const bf16x8 bl = *(const bf16x8*)(wmnl + bo);
            o0 = __builtin_amdgcn_mfma_f32_32x32x16_bf16(ah0, bh, o0, 0, 0, 0);
            o0 = __builtin_amdgcn_mfma_f32_32x32x16_bf16(ah0, bl, o0, 0, 0, 0);
            o0 = __builtin_amdgcn_mfma_f32_32x32x16_bf16(al0, bh, o0, 0, 0, 0);
            o1 = __builtin_amdgcn_mfma_f32_32x32x16_bf16(ah1, bh, o1, 0, 0, 0);
            o1 = __builtin_amdgcn_mfma_f32_32x32x16_bf16(ah1, bl, o1, 0, 0, 0);
            o1 = __builtin_amdgcn_mfma_f32_32x32x16_bf16(al1, bh, o1, 0, 0, 0);
        }
        const int gcol = nt * 32 + lm;
        if (gcol < FOUT_) {
            const float bv = b_mask[gcol];
#pragma unroll
            for (int e = 0; e < 16; ++e) {
                const int rowl = (e & 3) + 8 * (e >> 2) + 4 * hh;
                float x0 = o0[e] + bv, x1 = o1[e] + bv;
                out[(size_t)(m0 + rowl) * FOUT_ + gcol] = 1.f / (1.f + expf(-x0));
                out[(size_t)(m0 + 32 + rowl) * FOUT_ + gcol] = 1.f / (1.f + expf(-x1));
            }
        }
    }
}

// ---------------------------------------------------------------------------
extern "C" void kernel_launch(void* const* d_in, const int* in_sizes, int n_in,
                              void* d_out, int out_size, void* d_ws, size_t ws_size,
                              hipStream_t stream)
{
    const float* k       = (const float*)d_in[0];
    const float* q       = (const float*)d_in[1];
    const float* W_score = (const float*)d_in[2];
    const float* W_enh   = (const float*)d_in[3];
    const float* b_enh   = (const float*)d_in[4];
    const float* W_mask  = (const float*)d_in[5];
    const float* b_mask  = (const float*)d_in[6];
    float* out = (float*)d_out;

    const size_t MH = (size_t)B_ * T_ * H_;          // 4.096M elems
    unsigned short* q2h = (unsigned short*)d_ws;
    unsigned short* q2l = q2h + MH;
    unsigned short* ch  = q2l + MH;
    unsigned short* cl  = ch + MH;
    unsigned short* kh  = cl + MH;
    unsigned short* kl  = kh + MH;
    unsigned short* ktn = kl + MH;                   // 8*16*126*256
    unsigned short* wsnh = ktn + (size_t)B_ * 16 * 126 * 256;
    unsigned short* wsnl = wsnh + 65536;
    unsigned short* weh  = wsnl + 65536;
    unsigned short* wel  = weh + 131072;
    unsigned short* wmnh = wel + 131072;             // 320x256 frag-ordered
    unsigned short* wmnl = wmnh + 81920;

    dim3 blk(256);

    prep<<<dim3(4288), blk, 0, stream>>>(
        k, q, W_score, W_enh, W_mask,
        q2h, q2l, kh, kl, ktn, wsnh, wsnl, weh, wel, wmnh, wmnl);

    band_attn_mfma<<<dim3(504), dim3(512), 0, stream>>>(
        q2h, q2l, wsnh, wsnl, kh, kl, ktn, ch, cl);

    gemm_enh_out<<<dim3(250), blk, 0, stream>>>(
        ch, cl, q2h, q2l, weh, wel, b_enh, wmnh, wmnl, b_mask, out);
}

// Round 17
// 96.713 us; speedup vs baseline: 1.3317x; 1.1576x over previous
//
#include <hip/hip_runtime.h>
#include <math.h>

#define B_    8
#define T_    2000
#define H_    256
#define FOUT_ 257
#define ALEN_ 128

typedef __attribute__((ext_vector_type(8))) short bf16x8;
typedef __attribute__((ext_vector_type(4))) float f32x4;
typedef __attribute__((ext_vector_type(8))) unsigned short u16x8;

// ---------------------------------------------------------------------------
// truncation split: x = hi + lo exactly at f32
__device__ __forceinline__ void split1(float x, unsigned short& h, unsigned short& l) {
    unsigned u = __builtin_bit_cast(unsigned, x);
    h = (unsigned short)(u >> 16);
    float hf = __builtin_bit_cast(float, u & 0xFFFF0000u);
    l = (unsigned short)(__builtin_bit_cast(unsigned, x - hf) >> 16);
}
__device__ __forceinline__ void split8(float4 f0, float4 f1, bf16x8& h, bf16x8& l) {
    float f[8] = {f0.x, f0.y, f0.z, f0.w, f1.x, f1.y, f1.z, f1.w};
#pragma unroll
    for (int i = 0; i < 8; ++i) {
        unsigned short hh, ll;
        split1(f[i], hh, ll);
        h[i] = (short)hh; l[i] = (short)ll;
    }
}

// FA (frag-ordered) layout, keyed (row, k), KF = K/32 frags per 16-row tile:
//   rt=row>>4, rr=row&15, kf=k>>5, q=(k>>3)&3, e=k&7
//   elem offset = (((rt*KF + kf)*4 + q)*16 + rr)*8 + e
// A wave's frag (rt,kf) load = base (rt*KF+kf)*1024B + lane*16B (contiguous 1KB).

// ---------------------------------------------------------------------------
// prep:
//  [0,2000):    q -> q2 FA (KF=8)
//  [2000,3008): k -> kFA (KF=8)  +  ktn (PV-frag-ordered bf16-hi, unchanged)
//  [3008,3264): W_score -> wsn (== FA(col,k) KF=8, attn phase-0 B)
//  [3264,3776): W_enh -> wen FA(col,k) KF=16 (gemm_enh B)
//  [3776,4288): W_mask -> wmn FA(col,k) KF=8, cols padded to 320 (zeros >=257)
__global__ __launch_bounds__(256) void prep(
    const float* __restrict__ k, const float* __restrict__ q,
    const float* __restrict__ Ws, const float* __restrict__ We,
    const float* __restrict__ Wm,
    unsigned short* __restrict__ q2h, unsigned short* __restrict__ q2l,
    unsigned short* __restrict__ kfh, unsigned short* __restrict__ kfl,
    unsigned short* __restrict__ ktn,
    unsigned short* __restrict__ wsnh, unsigned short* __restrict__ wsnl,
    unsigned short* __restrict__ wenh, unsigned short* __restrict__ wenl,
    unsigned short* __restrict__ wmnh, unsigned short* __restrict__ wmnl)
{
    __shared__ float tile[16][260];
    const int bx = blockIdx.x, tid = threadIdx.x;

    if (bx < 2000) {                     // ---- q split -> FA
        const size_t i = ((size_t)bx * 256 + tid) * 8;
        const int row = (int)(i >> 8), kb2 = (int)(i & 255);
        const float4 f0 = *(const float4*)(q + i);
        const float4 f1 = *(const float4*)(q + i + 4);
        bf16x8 h, l;
        split8(f0, f1, h, l);
        const size_t off = ((((size_t)(row >> 4) * 8 + (kb2 >> 5)) * 4 +
                             ((kb2 >> 3) & 3)) * 16 + (row & 15)) * 8;
        *(bf16x8*)(q2h + off) = h;
        *(bf16x8*)(q2l + off) = l;
    } else if (bx < 3008) {              // ---- k prep: kFA + ktn
        const int bid = bx - 2000;
        const int b = bid / 126;
        const int g = bid % 126;
        const int s0 = g * 16;
        const int r = tid >> 4, cs = (tid & 15) * 16;
        const int s = s0 + r;
        if (s < T_) {
            const float* src = k + ((size_t)b * T_ + s) * H_ + cs;
#pragma unroll
            for (int i = 0; i < 2; ++i) {
                const float4 v0 = *(const float4*)(src + i * 8);
                const float4 v1 = *(const float4*)(src + i * 8 + 4);
                bf16x8 h, l;
                split8(v0, v1, h, l);
                const int kcol = cs + i * 8;
                const size_t off = ((((size_t)(b * 125 + g) * 8 + (kcol >> 5)) * 4 +
                                     ((kcol >> 3) & 3)) * 16 + r) * 8;
                *(bf16x8*)(kfh + off) = h;
                *(bf16x8*)(kfl + off) = l;
                const float ff[8] = {v0.x, v0.y, v0.z, v0.w, v1.x, v1.y, v1.z, v1.w};
#pragma unroll
                for (int j = 0; j < 8; ++j) tile[r][cs + i * 8 + j] = ff[j];
            }
        } else {
#pragma unroll
            for (int i = 0; i < 16; ++i) tile[r][cs + i] = 0.f;
        }
        __syncthreads();
        const int h = tid;
        const int ht = h >> 4, lq = h & 15;
        u16x8 o0, o1;
#pragma unroll
        for (int ss = 0; ss < 8; ++ss)
            o0[ss] = (unsigned short)(__builtin_bit_cast(unsigned, tile[ss][h]) >> 16);
#pragma unroll
        for (int ss = 0; ss < 8; ++ss)
            o1[ss] = (unsigned short)(__builtin_bit_cast(unsigned, tile[ss + 8][h]) >> 16);
        unsigned short* dst = ktn + (((size_t)(b * 16 + ht) * 126) + g) * 256 + lq * 8;
        *(u16x8*)(dst) = o0;
        *(u16x8*)(dst + 128) = o1;
    } else if (bx < 3264) {              // ---- W_score -> wsn (FA KF=8)
        const int g = bx - 3008;         // col (score col) 0..255
        const int kk = tid;              // k 0..255
        unsigned short h, l; split1(Ws[g * 256 + kk], h, l);
        const size_t off = ((((size_t)(g >> 4) * 8 + (kk >> 5)) * 4 +
                             ((kk >> 3) & 3)) * 16 + (g & 15)) * 8 + (kk & 7);
        wsnh[off] = h; wsnl[off] = l;
    } else if (bx < 3776) {              // ---- W_enh -> wen (FA KF=16)
        const int idx = (bx - 3264) * 256 + tid;  // 0..131071
        const int col = idx >> 9;         // enh col 0..255
        const int kk = idx & 511;         // k 0..511
        unsigned short h, l; split1(We[idx], h, l);
        const size_t off = ((((size_t)(col >> 4) * 16 + (kk >> 5)) * 4 +
                             ((kk >> 3) & 3)) * 16 + (col & 15)) * 8 + (kk & 7);
        wenh[off] = h; wenl[off] = l;
    } else {                             // ---- W_mask -> wmn (FA KF=8, 320 cols)
        const int col = bx - 3776;       // out col 0..511
        if (col < 320) {
            const int kk = tid;
            const float x = (col < FOUT_) ? Wm[col * 256 + kk] : 0.f;
            unsigned short h, l; split1(x, h, l);
            const size_t off = ((((size_t)(col >> 4) * 8 + (kk >> 5)) * 4 +
                                 ((kk >> 3) & 3)) * 16 + (col & 15)) * 8 + (kk & 7);
            wmnh[off] = h; wmnl[off] = l;
        }
    }
}

// ---------------------------------------------------------------------------
// Fused banded attention v7: structure = R16-proven v6; all global operands
// now FA-ordered (coalesced 1KB wave loads): phase-0 A from q2FA, QK^T B from
// kFA, c written FA (KF=8) for gemm_enh. 32-q blocks, 512 thr, b=bid&7.
__global__ __launch_bounds__(512) void band_attn_mfma(
    const unsigned short* __restrict__ q2h, const unsigned short* __restrict__ q2l,
    const unsigned short* __restrict__ wsnh, const unsigned short* __restrict__ wsnl,
    const unsigned short* __restrict__ kfh, const unsigned short* __restrict__ kfl,
    const unsigned short* __restrict__ ktn,
    unsigned short* __restrict__ Ch, unsigned short* __restrict__ Cl)
{
    __shared__ float S[32][164];
    __shared__ unsigned short PH[32][168];
    __shared__ unsigned short PL[32][168];
    __shared__ unsigned short QSH[32 * 256];
    __shared__ unsigned short QSL[32 * 256];

    const int bid = blockIdx.x;
    const int b = bid & 7;
    const int t0 = (bid >> 3) * 32;
    const int tid = threadIdx.x;
    const int w = tid >> 6, l = tid & 63;
    const int sub = w & 1;
    const int wp = w >> 1;
    const int lq = l & 15;
    const int lk = l >> 4;
    const int s_lo = max(0, t0 - ALEN_);
    const int srow = sub * 16;

    // ---- phase 0: qs(32 rows) = q2 @ Ws^T (3-term), D -> LDS ----
    {
        const int rtq = b * 125 + ((t0 + srow) >> 4);
        bf16x8 aH[8], aL[8];
#pragma unroll
        for (int kg = 0; kg < 8; ++kg) {
            const size_t ob = ((size_t)(rtq * 8 + kg)) * 1024 + (size_t)l * 16;
            aH[kg] = *(const bf16x8*)((const char*)q2h + ob);
            aL[kg] = *(const bf16x8*)((const char*)q2l + ob);
        }
        for (int ht = wp; ht < 16; ht += 4) {
            f32x4 acc = {};
#pragma unroll
            for (int kg = 0; kg < 8; ++kg) {
                const size_t fo = ((size_t)(ht * 8 + kg)) * 1024 + (size_t)l * 16;
                const bf16x8 bh = *(const bf16x8*)((const char*)wsnh + fo);
                const bf16x8 bl = *(const bf16x8*)((const char*)wsnl + fo);
                acc = __builtin_amdgcn_mfma_f32_16x16x32_bf16(aH[kg], bh, acc, 0, 0, 0);
                acc = __builtin_amdgcn_mfma_f32_16x16x32_bf16(aH[kg], bl, acc, 0, 0, 0);
                acc = __builtin_amdgcn_mfma_f32_16x16x32_bf16(aL[kg], bh, acc, 0, 0, 0);
            }
#pragma unroll
            for (int r = 0; r < 4; ++r) {
                unsigned short h2, l2;
                split1(acc[r], h2, l2);
                const int t = srow + lk * 4 + r;
                unsigned off = (unsigned)(t * 512 + (ht * 16 + lq) * 2);
                off ^= (unsigned)((t & 7) << 4);
                *(unsigned short*)((char*)QSH + off) = h2;
                *(unsigned short*)((char*)QSL + off) = l2;
            }
        }
    }
    __syncthreads();

    // ---- QK^T: A from LDS qs (own sub), B from kFA ----
    {
        bf16x8 aH[8], aL[8];
#pragma unroll
        for (int hc = 0; hc < 8; ++hc) {
            const int t = srow + lq;
            unsigned off = (unsigned)(t * 512 + hc * 64 + lk * 16);
            off ^= (unsigned)((t & 7) << 4);
            aH[hc] = *(const bf16x8*)((const char*)QSH + off);
            aL[hc] = *(const bf16x8*)((const char*)QSL + off);
        }
        const int slo16 = s_lo >> 4;
        for (int st = wp; st < 10; st += 4) {
            f32x4 acc = {};
            const int rtk = b * 125 + slo16 + st;
#pragma unroll
            for (int hc = 0; hc < 8; ++hc) {
                const size_t ob = ((size_t)(rtk * 8 + hc)) * 1024 + (size_t)l * 16;
                const bf16x8 bh = *(const bf16x8*)((const char*)kfh + ob);
                const bf16x8 bl = *(const bf16x8*)((const char*)kfl + ob);
                acc = __builtin_amdgcn_mfma_f32_16x16x32_bf16(aH[hc], bh, acc, 0, 0, 0);
                acc = __builtin_amdgcn_mfma_f32_16x16x32_bf16(aH[hc], bl, acc, 0, 0, 0);
                acc = __builtin_amdgcn_mfma_f32_16x16x32_bf16(aL[hc], bh, acc, 0, 0, 0);
            }
#pragma unroll
            for (int r = 0; r < 4; ++r)
                S[srow + lk * 4 + r][st * 16 + lq] = acc[r];
        }
    }
    __syncthreads();

    // ---- softmax (band-masked, P pre-scaled by 1/denom); 16 lanes/row ----
    {
        const int qq = tid >> 4, li = tid & 15;
        const int t = t0 + qq;
        const int jlo = max(0, t - ALEN_) - s_lo;
        const int jhi = t - s_lo;
        float m = -INFINITY;
#pragma unroll
        for (int j = 0; j < 10; ++j) {
            const int s = li + j * 16;
            if (s >= jlo && s <= jhi) m = fmaxf(m, S[qq][s]);
        }
#pragma unroll
        for (int off = 8; off; off >>= 1) m = fmaxf(m, __shfl_xor(m, off));
        float sum = 0.f;
#pragma unroll
        for (int j = 0; j < 10; ++j) {
            const int s = li + j * 16;
            const float e = (s >= jlo && s <= jhi) ? expf(S[qq][s] - m) : 0.f;
            S[qq][s] = e;
            sum += e;
        }
#pragma unroll
        for (int off = 8; off; off >>= 1) sum += __shfl_xor(sum, off);
        const float inv = 1.f / (sum + 1e-30f);
#pragma unroll
        for (int j = 0; j < 10; ++j) {
            const int s = li + j * 16;
            unsigned short hh2, ll2;
            split1(S[qq][s] * inv, hh2, ll2);
            PH[qq][s] = hh2;
            PL[qq][s] = ll2;
        }
    }
    __syncthreads();

    // ---- PV (frag-ordered ktn); write c in FA (KF=8) ----
    const int gbase = s_lo >> 4;
    for (int ht = wp; ht < 16; ht += 4) {
        f32x4 acc = {};
        const unsigned short* ktb = ktn + ((size_t)(b * 16 + ht) * 126) * 256;
#pragma unroll
        for (int sc = 0; sc < 5; ++sc) {
            const bf16x8 ph = *(const bf16x8*)((const char*)&PH[srow + lq][0] + sc * 64 + lk * 16);
            const bf16x8 pl = *(const bf16x8*)((const char*)&PL[srow + lq][0] + sc * 64 + lk * 16);
            const bf16x8 bt = *(const bf16x8*)(
                ktb + (size_t)(gbase + 2 * sc + (lk >> 1)) * 256 + (lk & 1) * 128 + lq * 8);
            acc = __builtin_amdgcn_mfma_f32_16x16x32_bf16(ph, bt, acc, 0, 0, 0);
            acc = __builtin_amdgcn_mfma_f32_16x16x32_bf16(pl, bt, acc, 0, 0, 0);
        }
        const int rt_c = b * 125 + ((t0 + srow) >> 4);
        const size_t base = (((size_t)rt_c * 8 + (ht >> 1)) * 4 +
                             ((ht & 1) * 2 + (lq >> 3))) * 16;
#pragma unroll
        for (int r = 0; r < 4; ++r) {
            const int trow = t0 + srow + lk * 4 + r;
            if (trow < T_) {
                unsigned short hh2, ll2;
                split1(acc[r], hh2, ll2);
                const size_t o = (base + (lk * 4 + r)) * 8 + (lq & 7);
                Ch[o] = hh2;
                Cl[o] = ll2;
            }
        }
    }
}

// ---------------------------------------------------------------------------
// gemm_enh: enh = tanh([c,q] @ We^T + be). No LDS, no barriers. Block = one
// 16-row tile (grid 1000), 4 waves; wave wp owns col-tiles {wp,wp+4,wp+8,wp+12}.
// Two phases (c then q) keep live A-frags at 8 pairs (64 VGPR). B streamed
// from wen FA (L2-resident, 1KB wave loads). Output enh in FA (KF=8).
__global__ __launch_bounds__(256) void gemm_enh(
    const unsigned short* __restrict__ ch, const unsigned short* __restrict__ cl,
    const unsigned short* __restrict__ qh, const unsigned short* __restrict__ ql,
    const unsigned short* __restrict__ wenh, const unsigned short* __restrict__ wenl,
    const float* __restrict__ b_enh,
    unsigned short* __restrict__ eh, unsigned short* __restrict__ el)
{
    const int rt = blockIdx.x;
    const int tid = threadIdx.x;
    const int wp = tid >> 6, l = tid & 63;
    const int lq = l & 15, lk = l >> 4;

    f32x4 acc[4] = {};

#pragma unroll
    for (int ph = 0; ph < 2; ++ph) {
        const unsigned short* Ah = ph ? qh : ch;
        const unsigned short* Al = ph ? ql : cl;
        bf16x8 aH[8], aL[8];
#pragma unroll
        for (int kf = 0; kf < 8; ++kf) {
            const size_t ob = ((size_t)(rt * 8 + kf)) * 1024 + (size_t)l * 16;
            aH[kf] = *(const bf16x8*)((const char*)Ah + ob);
            aL[kf] = *(const bf16x8*)((const char*)Al + ob);
        }
#pragma unroll
        for (int i = 0; i < 4; ++i) {
            const int ct = wp + i * 4;
#pragma unroll
            for (int kf = 0; kf < 8; ++kf) {
                const size_t bo = ((size_t)(ct * 16 + ph * 8 + kf)) * 1024 + (size_t)l * 16;
                const bf16x8 bh = *(const bf16x8*)((const char*)wenh + bo);
                const bf16x8 bl = *(const bf16x8*)((const char*)wenl + bo);
                acc[i] = __builtin_amdgcn_mfma_f32_16x16x32_bf16(aH[kf], bh, acc[i], 0, 0, 0);
                acc[i] = __builtin_amdgcn_mfma_f32_16x16x32_bf16(aH[kf], bl, acc[i], 0, 0, 0);
                acc[i] = __builtin_amdgcn_mfma_f32_16x16x32_bf16(aL[kf], bh, acc[i], 0, 0, 0);
            }
        }
    }

    // epilogue: D col=l&15, row=(l>>4)*4+r; enh(row rr, col) -> FA (KF=8)
#pragma unroll
    for (int i = 0; i < 4; ++i) {
        const int ct = wp + i * 4;
        const int col = ct * 16 + lq;
        const float bv = b_enh[col];
        const size_t base = (((size_t)rt * 8 + (ct >> 1)) * 4 +
                             ((ct & 1) * 2 + (lq >> 3))) * 16;
#pragma unroll
        for (int r = 0; r < 4; ++r) {
            unsigned short h2, l2;
            split1(tanhf(acc[i][r] + bv), h2, l2);
            const size_t o = (base + (lk * 4 + r)) * 8 + (lq & 7);
            eh[o] = h2;
            el[o] = l2;
        }
    }
}

// ---------------------------------------------------------------------------
// gemm_out: out = sigmoid(enh @ Wm^T + bm). No LDS, no barriers. Block = one
// 16-row tile (grid 1000), 4 waves; wave wp owns col-tiles {wp,wp+4,...,wp+16}
// (guarded ct<=16; cols >=257 masked at store). f32 row-major output.
__global__ __launch_bounds__(256) void gemm_out(
    const unsigned short* __restrict__ eh, const unsigned short* __restrict__ el,
    const unsigned short* __restrict__ wmnh, const unsigned short* __restrict__ wmnl,
    const float* __restrict__ b_mask, float* __restrict__ out)
{
    const int rt = blockIdx.x;
    const int tid = threadIdx.x;
    const int wp = tid >> 6, l = tid & 63;
    const int lq = l & 15, lk = l >> 4;

    bf16x8 aH[8], aL[8];
#pragma unroll
    for (int kf = 0; kf < 8; ++kf) {
        const size_t ob = ((size_t)(rt * 8 + kf)) * 1024 + (size_t)l * 16;
        aH[kf] = *(const bf16x8*)((const char*)eh + ob);
        aL[kf] = *(const bf16x8*)((const char*)el + ob);
    }

#pragma unroll
    for (int i = 0; i < 5; ++i) {
        const int ct = wp + i * 4;
        if (ct <= 16) {
            f32x4 acc = {};
#pragma unroll
            for (int kf = 0; kf < 8; ++kf) {
                const size_t bo = ((size_t)(ct * 8 + kf)) * 1024 + (size_t)l * 16;
                const bf16x8 bh = *(const bf16x8*)((const char*)wmnh + bo);
                const bf16x8 bl = *(const bf16x8*)((const char*)wmnl + bo);
                acc = __builtin_amdgcn_mfma_f32_16x16x32_bf16(aH[kf], bh, acc, 0, 0, 0);
                acc = __builtin_amdgcn_mfma_f32_16x16x32_bf16(aH[kf], bl, acc, 0, 0, 0);
                acc = __builtin_amdgcn_mfma_f32_16x16x32_bf16(aL[kf], bh, acc, 0, 0, 0);
            }
            const int col = ct * 16 + lq;
            if (col < FOUT_) {
                const float bv = b_mask[col];
#pragma unroll
                for (int r = 0; r < 4; ++r) {
                    const int row = rt * 16 + lk * 4 + r;
                    out[(size_t)row * FOUT_ + col] = 1.f / (1.f + expf(-(acc[r] + bv)));
                }
            }
        }
    }
}

// ---------------------------------------------------------------------------
extern "C" void kernel_launch(void* const* d_in, const int* in_sizes, int n_in,
                              void* d_out, int out_size, void* d_ws, size_t ws_size,
                              hipStream_t stream)
{
    const float* k       = (const float*)d_in[0];
    const float* q       = (const float*)d_in[1];
    const float* W_score = (const float*)d_in[2];
    const float* W_enh   = (const float*)d_in[3];
    const float* b_enh   = (const float*)d_in[4];
    const float* W_mask  = (const float*)d_in[5];
    const float* b_mask  = (const float*)d_in[6];
    float* out = (float*)d_out;

    const size_t MH = (size_t)B_ * T_ * H_;          // 4.096M elems
    unsigned short* q2h = (unsigned short*)d_ws;
    unsigned short* q2l = q2h + MH;
    unsigned short* ch  = q2l + MH;
    unsigned short* cl  = ch + MH;
    unsigned short* kfh = cl + MH;
    unsigned short* kfl = kfh + MH;
    unsigned short* eh  = kfl + MH;
    unsigned short* el  = eh + MH;
    unsigned short* ktn = el + MH;                   // 8*16*126*256
    unsigned short* wsnh = ktn + (size_t)B_ * 16 * 126 * 256;
    unsigned short* wsnl = wsnh + 65536;
    unsigned short* wenh = wsnl + 65536;
    unsigned short* wenl = wenh + 131072;
    unsigned short* wmnh = wenl + 131072;            // 320x256 FA
    unsigned short* wml  = wmnh + 81920;
    unsigned short* wmnl = wml;

    dim3 blk(256);

    prep<<<dim3(4288), blk, 0, stream>>>(
        k, q, W_score, W_enh, W_mask,
        q2h, q2l, kfh, kfl, ktn, wsnh, wsnl, wenh, wenl, wmnh, wmnl);

    band_attn_mfma<<<dim3(504), dim3(512), 0, stream>>>(
        q2h, q2l, wsnh, wsnl, kfh, kfl, ktn, ch, cl);

    gemm_enh<<<dim3(1000), blk, 0, stream>>>(
        ch, cl, q2h, q2l, wenh, wenl, b_enh, eh, el);

    gemm_out<<<dim3(1000), blk, 0, stream>>>(
        eh, el, wmnh, wmnl, b_mask, out);
}

// Round 18
// 87.721 us; speedup vs baseline: 1.4683x; 1.1025x over previous
//
#include <hip/hip_runtime.h>
#include <math.h>

#define B_    8
#define T_    2000
#define H_    256
#define FOUT_ 257
#define ALEN_ 128

typedef __attribute__((ext_vector_type(8))) short bf16x8;
typedef __attribute__((ext_vector_type(4))) float f32x4;
typedef __attribute__((ext_vector_type(8))) unsigned short u16x8;

// ---------------------------------------------------------------------------
// truncation split: x = hi + lo exactly at f32
__device__ __forceinline__ void split1(float x, unsigned short& h, unsigned short& l) {
    unsigned u = __builtin_bit_cast(unsigned, x);
    h = (unsigned short)(u >> 16);
    float hf = __builtin_bit_cast(float, u & 0xFFFF0000u);
    l = (unsigned short)(__builtin_bit_cast(unsigned, x - hf) >> 16);
}
__device__ __forceinline__ void split8(float4 f0, float4 f1, bf16x8& h, bf16x8& l) {
    float f[8] = {f0.x, f0.y, f0.z, f0.w, f1.x, f1.y, f1.z, f1.w};
#pragma unroll
    for (int i = 0; i < 8; ++i) {
        unsigned short hh, ll;
        split1(f[i], hh, ll);
        h[i] = (short)hh; l[i] = (short)ll;
    }
}

// FA (frag-ordered) layout, keyed (row, k), KF = K/32 frags per 16-row tile:
//   rt=row>>4, rr=row&15, kf=k>>5, q=(k>>3)&3, e=k&7
//   elem offset = (((rt*KF + kf)*4 + q)*16 + rr)*8 + e
// A wave's frag (rt,kf) load = base (rt*KF+kf)*1024B + lane*16B (contiguous 1KB).

// ---------------------------------------------------------------------------
// prep (R17-proven, unchanged):
//  [0,2000):    q -> q2 FA (KF=8)
//  [2000,3008): k -> kFA (KF=8)  +  ktn (PV-frag-ordered bf16-hi)
//  [3008,3264): W_score -> wsn FA(col,k) KF=8
//  [3264,3776): W_enh -> wen FA(col,k) KF=16
//  [3776,4288): W_mask -> wmn FA(col,k) KF=8, cols padded to 320 (zeros >=257)
__global__ __launch_bounds__(256) void prep(
    const float* __restrict__ k, const float* __restrict__ q,
    const float* __restrict__ Ws, const float* __restrict__ We,
    const float* __restrict__ Wm,
    unsigned short* __restrict__ q2h, unsigned short* __restrict__ q2l,
    unsigned short* __restrict__ kfh, unsigned short* __restrict__ kfl,
    unsigned short* __restrict__ ktn,
    unsigned short* __restrict__ wsnh, unsigned short* __restrict__ wsnl,
    unsigned short* __restrict__ wenh, unsigned short* __restrict__ wenl,
    unsigned short* __restrict__ wmnh, unsigned short* __restrict__ wmnl)
{
    __shared__ float tile[16][260];
    const int bx = blockIdx.x, tid = threadIdx.x;

    if (bx < 2000) {                     // ---- q split -> FA
        const size_t i = ((size_t)bx * 256 + tid) * 8;
        const int row = (int)(i >> 8), kb2 = (int)(i & 255);
        const float4 f0 = *(const float4*)(q + i);
        const float4 f1 = *(const float4*)(q + i + 4);
        bf16x8 h, l;
        split8(f0, f1, h, l);
        const size_t off = ((((size_t)(row >> 4) * 8 + (kb2 >> 5)) * 4 +
                             ((kb2 >> 3) & 3)) * 16 + (row & 15)) * 8;
        *(bf16x8*)(q2h + off) = h;
        *(bf16x8*)(q2l + off) = l;
    } else if (bx < 3008) {              // ---- k prep: kFA + ktn
        const int bid = bx - 2000;
        const int b = bid / 126;
        const int g = bid % 126;
        const int s0 = g * 16;
        const int r = tid >> 4, cs = (tid & 15) * 16;
        const int s = s0 + r;
        if (s < T_) {
            const float* src = k + ((size_t)b * T_ + s) * H_ + cs;
#pragma unroll
            for (int i = 0; i < 2; ++i) {
                const float4 v0 = *(const float4*)(src + i * 8);
                const float4 v1 = *(const float4*)(src + i * 8 + 4);
                bf16x8 h, l;
                split8(v0, v1, h, l);
                const int kcol = cs + i * 8;
                const size_t off = ((((size_t)(b * 125 + g) * 8 + (kcol >> 5)) * 4 +
                                     ((kcol >> 3) & 3)) * 16 + r) * 8;
                *(bf16x8*)(kfh + off) = h;
                *(bf16x8*)(kfl + off) = l;
                const float ff[8] = {v0.x, v0.y, v0.z, v0.w, v1.x, v1.y, v1.z, v1.w};
#pragma unroll
                for (int j = 0; j < 8; ++j) tile[r][cs + i * 8 + j] = ff[j];
            }
        } else {
#pragma unroll
            for (int i = 0; i < 16; ++i) tile[r][cs + i] = 0.f;
        }
        __syncthreads();
        const int h = tid;
        const int ht = h >> 4, lq = h & 15;
        u16x8 o0, o1;
#pragma unroll
        for (int ss = 0; ss < 8; ++ss)
            o0[ss] = (unsigned short)(__builtin_bit_cast(unsigned, tile[ss][h]) >> 16);
#pragma unroll
        for (int ss = 0; ss < 8; ++ss)
            o1[ss] = (unsigned short)(__builtin_bit_cast(unsigned, tile[ss + 8][h]) >> 16);
        unsigned short* dst = ktn + (((size_t)(b * 16 + ht) * 126) + g) * 256 + lq * 8;
        *(u16x8*)(dst) = o0;
        *(u16x8*)(dst + 128) = o1;
    } else if (bx < 3264) {              // ---- W_score -> wsn (FA KF=8)
        const int g = bx - 3008;
        const int kk = tid;
        unsigned short h, l; split1(Ws[g * 256 + kk], h, l);
        const size_t off = ((((size_t)(g >> 4) * 8 + (kk >> 5)) * 4 +
                             ((kk >> 3) & 3)) * 16 + (g & 15)) * 8 + (kk & 7);
        wsnh[off] = h; wsnl[off] = l;
    } else if (bx < 3776) {              // ---- W_enh -> wen (FA KF=16)
        const int idx = (bx - 3264) * 256 + tid;
        const int col = idx >> 9;
        const int kk = idx & 511;
        unsigned short h, l; split1(We[idx], h, l);
        const size_t off = ((((size_t)(col >> 4) * 16 + (kk >> 5)) * 4 +
                             ((kk >> 3) & 3)) * 16 + (col & 15)) * 8 + (kk & 7);
        wenh[off] = h; wenl[off] = l;
    } else {                             // ---- W_mask -> wmn (FA KF=8, 320 cols)
        const int col = bx - 3776;
        if (col < 320) {
            const int kk = tid;
            const float x = (col < FOUT_) ? Wm[col * 256 + kk] : 0.f;
            unsigned short h, l; split1(x, h, l);
            const size_t off = ((((size_t)(col >> 4) * 8 + (kk >> 5)) * 4 +
                                 ((kk >> 3) & 3)) * 16 + (col & 15)) * 8 + (kk & 7);
            wmnh[off] = h; wmnl[off] = l;
        }
    }
}

// ---------------------------------------------------------------------------
// Fused banded attention v7 (R17-proven, unchanged): FA operands throughout;
// 32-q blocks, 512 thr, b=bid&7 XCD-local; c written FA (KF=8).
__global__ __launch_bounds__(512) void band_attn_mfma(
    const unsigned short* __restrict__ q2h, const unsigned short* __restrict__ q2l,
    const unsigned short* __restrict__ wsnh, const unsigned short* __restrict__ wsnl,
    const unsigned short* __restrict__ kfh, const unsigned short* __restrict__ kfl,
    const unsigned short* __restrict__ ktn,
    unsigned short* __restrict__ Ch, unsigned short* __restrict__ Cl)
{
    __shared__ float S[32][164];
    __shared__ unsigned short PH[32][168];
    __shared__ unsigned short PL[32][168];
    __shared__ unsigned short QSH[32 * 256];
    __shared__ unsigned short QSL[32 * 256];

    const int bid = blockIdx.x;
    const int b = bid & 7;
    const int t0 = (bid >> 3) * 32;
    const int tid = threadIdx.x;
    const int w = tid >> 6, l = tid & 63;
    const int sub = w & 1;
    const int wp = w >> 1;
    const int lq = l & 15;
    const int lk = l >> 4;
    const int s_lo = max(0, t0 - ALEN_);
    const int srow = sub * 16;

    // ---- phase 0: qs(32 rows) = q2 @ Ws^T (3-term), D -> LDS ----
    {
        const int rtq = b * 125 + ((t0 + srow) >> 4);
        bf16x8 aH[8], aL[8];
#pragma unroll
        for (int kg = 0; kg < 8; ++kg) {
            const size_t ob = ((size_t)(rtq * 8 + kg)) * 1024 + (size_t)l * 16;
            aH[kg] = *(const bf16x8*)((const char*)q2h + ob);
            aL[kg] = *(const bf16x8*)((const char*)q2l + ob);
        }
        for (int ht = wp; ht < 16; ht += 4) {
            f32x4 acc = {};
#pragma unroll
            for (int kg = 0; kg < 8; ++kg) {
                const size_t fo = ((size_t)(ht * 8 + kg)) * 1024 + (size_t)l * 16;
                const bf16x8 bh = *(const bf16x8*)((const char*)wsnh + fo);
                const bf16x8 bl = *(const bf16x8*)((const char*)wsnl + fo);
                acc = __builtin_amdgcn_mfma_f32_16x16x32_bf16(aH[kg], bh, acc, 0, 0, 0);
                acc = __builtin_amdgcn_mfma_f32_16x16x32_bf16(aH[kg], bl, acc, 0, 0, 0);
                acc = __builtin_amdgcn_mfma_f32_16x16x32_bf16(aL[kg], bh, acc, 0, 0, 0);
            }
#pragma unroll
            for (int r = 0; r < 4; ++r) {
                unsigned short h2, l2;
                split1(acc[r], h2, l2);
                const int t = srow + lk * 4 + r;
                unsigned off = (unsigned)(t * 512 + (ht * 16 + lq) * 2);
                off ^= (unsigned)((t & 7) << 4);
                *(unsigned short*)((char*)QSH + off) = h2;
                *(unsigned short*)((char*)QSL + off) = l2;
            }
        }
    }
    __syncthreads();

    // ---- QK^T: A from LDS qs (own sub), B from kFA ----
    {
        bf16x8 aH[8], aL[8];
#pragma unroll
        for (int hc = 0; hc < 8; ++hc) {
            const int t = srow + lq;
            unsigned off = (unsigned)(t * 512 + hc * 64 + lk * 16);
            off ^= (unsigned)((t & 7) << 4);
            aH[hc] = *(const bf16x8*)((const char*)QSH + off);
            aL[hc] = *(const bf16x8*)((const char*)QSL + off);
        }
        const int slo16 = s_lo >> 4;
        for (int st = wp; st < 10; st += 4) {
            f32x4 acc = {};
            const int rtk = b * 125 + slo16 + st;
#pragma unroll
            for (int hc = 0; hc < 8; ++hc) {
                const size_t ob = ((size_t)(rtk * 8 + hc)) * 1024 + (size_t)l * 16;
                const bf16x8 bh = *(const bf16x8*)((const char*)kfh + ob);
                const bf16x8 bl = *(const bf16x8*)((const char*)kfl + ob);
                acc = __builtin_amdgcn_mfma_f32_16x16x32_bf16(aH[hc], bh, acc, 0, 0, 0);
                acc = __builtin_amdgcn_mfma_f32_16x16x32_bf16(aH[hc], bl, acc, 0, 0, 0);
                acc = __builtin_amdgcn_mfma_f32_16x16x32_bf16(aL[hc], bh, acc, 0, 0, 0);
            }
#pragma unroll
            for (int r = 0; r < 4; ++r)
                S[srow + lk * 4 + r][st * 16 + lq] = acc[r];
        }
    }
    __syncthreads();

    // ---- softmax (band-masked, P pre-scaled by 1/denom); 16 lanes/row ----
    {
        const int qq = tid >> 4, li = tid & 15;
        const int t = t0 + qq;
        const int jlo = max(0, t - ALEN_) - s_lo;
        const int jhi = t - s_lo;
        float m = -INFINITY;
#pragma unroll
        for (int j = 0; j < 10; ++j) {
            const int s = li + j * 16;
            if (s >= jlo && s <= jhi) m = fmaxf(m, S[qq][s]);
        }
#pragma unroll
        for (int off = 8; off; off >>= 1) m = fmaxf(m, __shfl_xor(m, off));
        float sum = 0.f;
#pragma unroll
        for (int j = 0; j < 10; ++j) {
            const int s = li + j * 16;
            const float e = (s >= jlo && s <= jhi) ? expf(S[qq][s] - m) : 0.f;
            S[qq][s] = e;
            sum += e;
        }
#pragma unroll
        for (int off = 8; off; off >>= 1) sum += __shfl_xor(sum, off);
        const float inv = 1.f / (sum + 1e-30f);
#pragma unroll
        for (int j = 0; j < 10; ++j) {
            const int s = li + j * 16;
            unsigned short hh2, ll2;
            split1(S[qq][s] * inv, hh2, ll2);
            PH[qq][s] = hh2;
            PL[qq][s] = ll2;
        }
    }
    __syncthreads();

    // ---- PV (frag-ordered ktn); write c in FA (KF=8) ----
    const int gbase = s_lo >> 4;
    for (int ht = wp; ht < 16; ht += 4) {
        f32x4 acc = {};
        const unsigned short* ktb = ktn + ((size_t)(b * 16 + ht) * 126) * 256;
#pragma unroll
        for (int sc = 0; sc < 5; ++sc) {
            const bf16x8 ph = *(const bf16x8*)((const char*)&PH[srow + lq][0] + sc * 64 + lk * 16);
            const bf16x8 pl = *(const bf16x8*)((const char*)&PL[srow + lq][0] + sc * 64 + lk * 16);
            const bf16x8 bt = *(const bf16x8*)(
                ktb + (size_t)(gbase + 2 * sc + (lk >> 1)) * 256 + (lk & 1) * 128 + lq * 8);
            acc = __builtin_amdgcn_mfma_f32_16x16x32_bf16(ph, bt, acc, 0, 0, 0);
            acc = __builtin_amdgcn_mfma_f32_16x16x32_bf16(pl, bt, acc, 0, 0, 0);
        }
        const int rt_c = b * 125 + ((t0 + srow) >> 4);
        const size_t base = (((size_t)rt_c * 8 + (ht >> 1)) * 4 +
                             ((ht & 1) * 2 + (lq >> 3))) * 16;
#pragma unroll
        for (int r = 0; r < 4; ++r) {
            const int trow = t0 + srow + lk * 4 + r;
            if (trow < T_) {
                unsigned short hh2, ll2;
                split1(acc[r], hh2, ll2);
                const size_t o = (base + (lk * 4 + r)) * 8 + (lq & 7);
                Ch[o] = hh2;
                Cl[o] = ll2;
            }
        }
    }
}

// ---------------------------------------------------------------------------
// gemm_fused: enh = tanh([c,q] @ We^T + be) -> LDS -> out = sigmoid(enh @
// Wm^T + bm). Merges R17's gemm_enh + gemm_out: same 16-row block (grid 1000),
// 4 waves, streaming FA operands, no staging pipeline. enh passes through a
// 16KB swizzled LDS tile (QS pattern, conflict-free both sides) — eliminates
// the 33MB eh/el HBM round-trip and one launch. Arithmetic identical to R17.
__global__ __launch_bounds__(256) void gemm_fused(
    const unsigned short* __restrict__ ch, const unsigned short* __restrict__ cl,
    const unsigned short* __restrict__ qh, const unsigned short* __restrict__ ql,
    const unsigned short* __restrict__ wenh, const unsigned short* __restrict__ wenl,
    const float* __restrict__ b_enh,
    const unsigned short* __restrict__ wmnh, const unsigned short* __restrict__ wmnl,
    const float* __restrict__ b_mask, float* __restrict__ out)
{
    __shared__ unsigned short EH[16 * 256];
    __shared__ unsigned short EL[16 * 256];

    const int rt = blockIdx.x;
    const int tid = threadIdx.x;
    const int wp = tid >> 6, l = tid & 63;
    const int lq = l & 15, lk = l >> 4;

    // ---- phase 1: enh tile (16 x 256), acc[i] = col-tile wp + i*4 ----
    f32x4 acc[4] = {};
#pragma unroll
    for (int ph = 0; ph < 2; ++ph) {
        const unsigned short* Ah = ph ? qh : ch;
        const unsigned short* Al = ph ? ql : cl;
        bf16x8 aH[8], aL[8];
#pragma unroll
        for (int kf = 0; kf < 8; ++kf) {
            const size_t ob = ((size_t)(rt * 8 + kf)) * 1024 + (size_t)l * 16;
            aH[kf] = *(const bf16x8*)((const char*)Ah + ob);
            aL[kf] = *(const bf16x8*)((const char*)Al + ob);
        }
#pragma unroll
        for (int i = 0; i < 4; ++i) {
            const int ct = wp + i * 4;
#pragma unroll
            for (int kf = 0; kf < 8; ++kf) {
                const size_t bo = ((size_t)(ct * 16 + ph * 8 + kf)) * 1024 + (size_t)l * 16;
                const bf16x8 bh = *(const bf16x8*)((const char*)wenh + bo);
                const bf16x8 bl = *(const bf16x8*)((const char*)wenl + bo);
                acc[i] = __builtin_amdgcn_mfma_f32_16x16x32_bf16(aH[kf], bh, acc[i], 0, 0, 0);
                acc[i] = __builtin_amdgcn_mfma_f32_16x16x32_bf16(aH[kf], bl, acc[i], 0, 0, 0);
                acc[i] = __builtin_amdgcn_mfma_f32_16x16x32_bf16(aL[kf], bh, acc[i], 0, 0, 0);
            }
        }
    }

    // ---- enh -> LDS (split, swizzled; D col=lq, row=lk*4+r) ----
#pragma unroll
    for (int i = 0; i < 4; ++i) {
        const int ct = wp + i * 4;
        const int col = ct * 16 + lq;
        const float bv = b_enh[col];
#pragma unroll
        for (int r = 0; r < 4; ++r) {
            const int row = lk * 4 + r;
            unsigned short h2, l2;
            split1(tanhf(acc[i][r] + bv), h2, l2);
            unsigned off = (unsigned)(row * 512 + col * 2);
            off ^= (unsigned)((row & 7) << 4);
            *(unsigned short*)((char*)EH + off) = h2;
            *(unsigned short*)((char*)EL + off) = l2;
        }
    }
    __syncthreads();

    // ---- phase 2: out = sigmoid(enh @ Wm^T + bm); A-frags from LDS ----
    bf16x8 aH[8], aL[8];
#pragma unroll
    for (int kf = 0; kf < 8; ++kf) {
        unsigned off = (unsigned)(lq * 512 + kf * 64 + lk * 16);
        off ^= (unsigned)((lq & 7) << 4);
        aH[kf] = *(const bf16x8*)((const char*)EH + off);
        aL[kf] = *(const bf16x8*)((const char*)EL + off);
    }
#pragma unroll
    for (int i = 0; i < 5; ++i) {
        const int ct = wp + i * 4;
        if (ct <= 16) {
            f32x4 o = {};
#pragma unroll
            for (int kf = 0; kf < 8; ++kf) {
                const size_t bo = ((size_t)(ct * 8 + kf)) * 1024 + (size_t)l * 16;
                const bf16x8 bh = *(const bf16x8*)((const char*)wmnh + bo);
                const bf16x8 bl = *(const bf16x8*)((const char*)wmnl + bo);
                o = __builtin_amdgcn_mfma_f32_16x16x32_bf16(aH[kf], bh, o, 0, 0, 0);
                o = __builtin_amdgcn_mfma_f32_16x16x32_bf16(aH[kf], bl, o, 0, 0, 0);
                o = __builtin_amdgcn_mfma_f32_16x16x32_bf16(aL[kf], bh, o, 0, 0, 0);
            }
            const int col = ct * 16 + lq;
            if (col < FOUT_) {
                const float bv = b_mask[col];
#pragma unroll
                for (int r = 0; r < 4; ++r) {
                    const int row = rt * 16 + lk * 4 + r;
                    out[(size_t)row * FOUT_ + col] = 1.f / (1.f + expf(-(o[r] + bv)));
                }
            }
        }
    }
}

// ---------------------------------------------------------------------------
extern "C" void kernel_launch(void* const* d_in, const int* in_sizes, int n_in,
                              void* d_out, int out_size, void* d_ws, size_t ws_size,
                              hipStream_t stream)
{
    const float* k       = (const float*)d_in[0];
    const float* q       = (const float*)d_in[1];
    const float* W_score = (const float*)d_in[2];
    const float* W_enh   = (const float*)d_in[3];
    const float* b_enh   = (const float*)d_in[4];
    const float* W_mask  = (const float*)d_in[5];
    const float* b_mask  = (const float*)d_in[6];
    float* out = (float*)d_out;

    const size_t MH = (size_t)B_ * T_ * H_;          // 4.096M elems
    unsigned short* q2h = (unsigned short*)d_ws;
    unsigned short* q2l = q2h + MH;
    unsigned short* ch  = q2l + MH;
    unsigned short* cl  = ch + MH;
    unsigned short* kfh = cl + MH;
    unsigned short* kfl = kfh + MH;
    unsigned short* ktn = kfl + MH;                  // 8*16*126*256
    unsigned short* wsnh = ktn + (size_t)B_ * 16 * 126 * 256;
    unsigned short* wsnl = wsnh + 65536;
    unsigned short* wenh = wsnl + 65536;
    unsigned short* wenl = wenh + 131072;
    unsigned short* wmnh = wenl + 131072;            // 320x256 FA
    unsigned short* wmnl = wmnh + 81920;

    dim3 blk(256);

    prep<<<dim3(4288), blk, 0, stream>>>(
        k, q, W_score, W_enh, W_mask,
        q2h, q2l, kfh, kfl, ktn, wsnh, wsnl, wenh, wenl, wmnh, wmnl);

    band_attn_mfma<<<dim3(504), dim3(512), 0, stream>>>(
        q2h, q2l, wsnh, wsnl, kfh, kfl, ktn, ch, cl);

    gemm_fused<<<dim3(1000), blk, 0, stream>>>(
        ch, cl, q2h, q2l, wenh, wenl, b_enh, wmnh, wmnl, b_mask, out);
}

// Round 19
// 85.683 us; speedup vs baseline: 1.5032x; 1.0238x over previous
//
#include <hip/hip_runtime.h>
#include <math.h>

#define B_    8
#define T_    2000
#define H_    256
#define FOUT_ 257
#define ALEN_ 128

typedef __attribute__((ext_vector_type(8))) short bf16x8;
typedef __attribute__((ext_vector_type(4))) float f32x4;
typedef __attribute__((ext_vector_type(8))) unsigned short u16x8;

// ---------------------------------------------------------------------------
// truncation split: x = hi + lo exactly at f32
__device__ __forceinline__ void split1(float x, unsigned short& h, unsigned short& l) {
    unsigned u = __builtin_bit_cast(unsigned, x);
    h = (unsigned short)(u >> 16);
    float hf = __builtin_bit_cast(float, u & 0xFFFF0000u);
    l = (unsigned short)(__builtin_bit_cast(unsigned, x - hf) >> 16);
}
__device__ __forceinline__ void split8(float4 f0, float4 f1, bf16x8& h, bf16x8& l) {
    float f[8] = {f0.x, f0.y, f0.z, f0.w, f1.x, f1.y, f1.z, f1.w};
#pragma unroll
    for (int i = 0; i < 8; ++i) {
        unsigned short hh, ll;
        split1(f[i], hh, ll);
        h[i] = (short)hh; l[i] = (short)ll;
    }
}

// FA (frag-ordered) layout, keyed (row, k), KF = K/32 frags per 16-row tile:
//   rt=row>>4, rr=row&15, kf=k>>5, q=(k>>3)&3, e=k&7
//   elem offset = (((rt*KF + kf)*4 + q)*16 + rr)*8 + e
// A wave's frag (rt,kf) load = base (rt*KF+kf)*1024B + lane*16B (contiguous 1KB).

// ---------------------------------------------------------------------------
// prep (R17-proven, unchanged).
__global__ __launch_bounds__(256) void prep(
    const float* __restrict__ k, const float* __restrict__ q,
    const float* __restrict__ Ws, const float* __restrict__ We,
    const float* __restrict__ Wm,
    unsigned short* __restrict__ q2h, unsigned short* __restrict__ q2l,
    unsigned short* __restrict__ kfh, unsigned short* __restrict__ kfl,
    unsigned short* __restrict__ ktn,
    unsigned short* __restrict__ wsnh, unsigned short* __restrict__ wsnl,
    unsigned short* __restrict__ wenh, unsigned short* __restrict__ wenl,
    unsigned short* __restrict__ wmnh, unsigned short* __restrict__ wmnl)
{
    __shared__ float tile[16][260];
    const int bx = blockIdx.x, tid = threadIdx.x;

    if (bx < 2000) {                     // ---- q split -> FA
        const size_t i = ((size_t)bx * 256 + tid) * 8;
        const int row = (int)(i >> 8), kb2 = (int)(i & 255);
        const float4 f0 = *(const float4*)(q + i);
        const float4 f1 = *(const float4*)(q + i + 4);
        bf16x8 h, l;
        split8(f0, f1, h, l);
        const size_t off = ((((size_t)(row >> 4) * 8 + (kb2 >> 5)) * 4 +
                             ((kb2 >> 3) & 3)) * 16 + (row & 15)) * 8;
        *(bf16x8*)(q2h + off) = h;
        *(bf16x8*)(q2l + off) = l;
    } else if (bx < 3008) {              // ---- k prep: kFA + ktn
        const int bid = bx - 2000;
        const int b = bid / 126;
        const int g = bid % 126;
        const int s0 = g * 16;
        const int r = tid >> 4, cs = (tid & 15) * 16;
        const int s = s0 + r;
        if (s < T_) {
            const float* src = k + ((size_t)b * T_ + s) * H_ + cs;
#pragma unroll
            for (int i = 0; i < 2; ++i) {
                const float4 v0 = *(const float4*)(src + i * 8);
                const float4 v1 = *(const float4*)(src + i * 8 + 4);
                bf16x8 h, l;
                split8(v0, v1, h, l);
                const int kcol = cs + i * 8;
                const size_t off = ((((size_t)(b * 125 + g) * 8 + (kcol >> 5)) * 4 +
                                     ((kcol >> 3) & 3)) * 16 + r) * 8;
                *(bf16x8*)(kfh + off) = h;
                *(bf16x8*)(kfl + off) = l;
                const float ff[8] = {v0.x, v0.y, v0.z, v0.w, v1.x, v1.y, v1.z, v1.w};
#pragma unroll
                for (int j = 0; j < 8; ++j) tile[r][cs + i * 8 + j] = ff[j];
            }
        } else {
#pragma unroll
            for (int i = 0; i < 16; ++i) tile[r][cs + i] = 0.f;
        }
        __syncthreads();
        const int h = tid;
        const int ht = h >> 4, lq = h & 15;
        u16x8 o0, o1;
#pragma unroll
        for (int ss = 0; ss < 8; ++ss)
            o0[ss] = (unsigned short)(__builtin_bit_cast(unsigned, tile[ss][h]) >> 16);
#pragma unroll
        for (int ss = 0; ss < 8; ++ss)
            o1[ss] = (unsigned short)(__builtin_bit_cast(unsigned, tile[ss + 8][h]) >> 16);
        unsigned short* dst = ktn + (((size_t)(b * 16 + ht) * 126) + g) * 256 + lq * 8;
        *(u16x8*)(dst) = o0;
        *(u16x8*)(dst + 128) = o1;
    } else if (bx < 3264) {              // ---- W_score -> wsn (FA KF=8)
        const int g = bx - 3008;
        const int kk = tid;
        unsigned short h, l; split1(Ws[g * 256 + kk], h, l);
        const size_t off = ((((size_t)(g >> 4) * 8 + (kk >> 5)) * 4 +
                             ((kk >> 3) & 3)) * 16 + (g & 15)) * 8 + (kk & 7);
        wsnh[off] = h; wsnl[off] = l;
    } else if (bx < 3776) {              // ---- W_enh -> wen (FA KF=16)
        const int idx = (bx - 3264) * 256 + tid;
        const int col = idx >> 9;
        const int kk = idx & 511;
        unsigned short h, l; split1(We[idx], h, l);
        const size_t off = ((((size_t)(col >> 4) * 16 + (kk >> 5)) * 4 +
                             ((kk >> 3) & 3)) * 16 + (col & 15)) * 8 + (kk & 7);
        wenh[off] = h; wenl[off] = l;
    } else {                             // ---- W_mask -> wmn (FA KF=8, 320 cols)
        const int col = bx - 3776;
        if (col < 320) {
            const int kk = tid;
            const float x = (col < FOUT_) ? Wm[col * 256 + kk] : 0.f;
            unsigned short h, l; split1(x, h, l);
            const size_t off = ((((size_t)(col >> 4) * 8 + (kk >> 5)) * 4 +
                                 ((kk >> 3) & 3)) * 16 + (col & 15)) * 8 + (kk & 7);
            wmnh[off] = h; wmnl[off] = l;
        }
    }
}

// ---------------------------------------------------------------------------
// Fused banded attention v7 (R17-proven, unchanged).
__global__ __launch_bounds__(512) void band_attn_mfma(
    const unsigned short* __restrict__ q2h, const unsigned short* __restrict__ q2l,
    const unsigned short* __restrict__ wsnh, const unsigned short* __restrict__ wsnl,
    const unsigned short* __restrict__ kfh, const unsigned short* __restrict__ kfl,
    const unsigned short* __restrict__ ktn,
    unsigned short* __restrict__ Ch, unsigned short* __restrict__ Cl)
{
    __shared__ float S[32][164];
    __shared__ unsigned short PH[32][168];
    __shared__ unsigned short PL[32][168];
    __shared__ unsigned short QSH[32 * 256];
    __shared__ unsigned short QSL[32 * 256];

    const int bid = blockIdx.x;
    const int b = bid & 7;
    const int t0 = (bid >> 3) * 32;
    const int tid = threadIdx.x;
    const int w = tid >> 6, l = tid & 63;
    const int sub = w & 1;
    const int wp = w >> 1;
    const int lq = l & 15;
    const int lk = l >> 4;
    const int s_lo = max(0, t0 - ALEN_);
    const int srow = sub * 16;

    // ---- phase 0: qs(32 rows) = q2 @ Ws^T (3-term), D -> LDS ----
    {
        const int rtq = b * 125 + ((t0 + srow) >> 4);
        bf16x8 aH[8], aL[8];
#pragma unroll
        for (int kg = 0; kg < 8; ++kg) {
            const size_t ob = ((size_t)(rtq * 8 + kg)) * 1024 + (size_t)l * 16;
            aH[kg] = *(const bf16x8*)((const char*)q2h + ob);
            aL[kg] = *(const bf16x8*)((const char*)q2l + ob);
        }
        for (int ht = wp; ht < 16; ht += 4) {
            f32x4 acc = {};
#pragma unroll
            for (int kg = 0; kg < 8; ++kg) {
                const size_t fo = ((size_t)(ht * 8 + kg)) * 1024 + (size_t)l * 16;
                const bf16x8 bh = *(const bf16x8*)((const char*)wsnh + fo);
                const bf16x8 bl = *(const bf16x8*)((const char*)wsnl + fo);
                acc = __builtin_amdgcn_mfma_f32_16x16x32_bf16(aH[kg], bh, acc, 0, 0, 0);
                acc = __builtin_amdgcn_mfma_f32_16x16x32_bf16(aH[kg], bl, acc, 0, 0, 0);
                acc = __builtin_amdgcn_mfma_f32_16x16x32_bf16(aL[kg], bh, acc, 0, 0, 0);
            }
#pragma unroll
            for (int r = 0; r < 4; ++r) {
                unsigned short h2, l2;
                split1(acc[r], h2, l2);
                const int t = srow + lk * 4 + r;
                unsigned off = (unsigned)(t * 512 + (ht * 16 + lq) * 2);
                off ^= (unsigned)((t & 7) << 4);
                *(unsigned short*)((char*)QSH + off) = h2;
                *(unsigned short*)((char*)QSL + off) = l2;
            }
        }
    }
    __syncthreads();

    // ---- QK^T: A from LDS qs (own sub), B from kFA ----
    {
        bf16x8 aH[8], aL[8];
#pragma unroll
        for (int hc = 0; hc < 8; ++hc) {
            const int t = srow + lq;
            unsigned off = (unsigned)(t * 512 + hc * 64 + lk * 16);
            off ^= (unsigned)((t & 7) << 4);
            aH[hc] = *(const bf16x8*)((const char*)QSH + off);
            aL[hc] = *(const bf16x8*)((const char*)QSL + off);
        }
        const int slo16 = s_lo >> 4;
        for (int st = wp; st < 10; st += 4) {
            f32x4 acc = {};
            const int rtk = b * 125 + slo16 + st;
#pragma unroll
            for (int hc = 0; hc < 8; ++hc) {
                const size_t ob = ((size_t)(rtk * 8 + hc)) * 1024 + (size_t)l * 16;
                const bf16x8 bh = *(const bf16x8*)((const char*)kfh + ob);
                const bf16x8 bl = *(const bf16x8*)((const char*)kfl + ob);
                acc = __builtin_amdgcn_mfma_f32_16x16x32_bf16(aH[hc], bh, acc, 0, 0, 0);
                acc = __builtin_amdgcn_mfma_f32_16x16x32_bf16(aH[hc], bl, acc, 0, 0, 0);
                acc = __builtin_amdgcn_mfma_f32_16x16x32_bf16(aL[hc], bh, acc, 0, 0, 0);
            }
#pragma unroll
            for (int r = 0; r < 4; ++r)
                S[srow + lk * 4 + r][st * 16 + lq] = acc[r];
        }
    }
    __syncthreads();

    // ---- softmax (band-masked, P pre-scaled by 1/denom); 16 lanes/row ----
    {
        const int qq = tid >> 4, li = tid & 15;
        const int t = t0 + qq;
        const int jlo = max(0, t - ALEN_) - s_lo;
        const int jhi = t - s_lo;
        float m = -INFINITY;
#pragma unroll
        for (int j = 0; j < 10; ++j) {
            const int s = li + j * 16;
            if (s >= jlo && s <= jhi) m = fmaxf(m, S[qq][s]);
        }
#pragma unroll
        for (int off = 8; off; off >>= 1) m = fmaxf(m, __shfl_xor(m, off));
        float sum = 0.f;
#pragma unroll
        for (int j = 0; j < 10; ++j) {
            const int s = li + j * 16;
            const float e = (s >= jlo && s <= jhi) ? expf(S[qq][s] - m) : 0.f;
            S[qq][s] = e;
            sum += e;
        }
#pragma unroll
        for (int off = 8; off; off >>= 1) sum += __shfl_xor(sum, off);
        const float inv = 1.f / (sum + 1e-30f);
#pragma unroll
        for (int j = 0; j < 10; ++j) {
            const int s = li + j * 16;
            unsigned short hh2, ll2;
            split1(S[qq][s] * inv, hh2, ll2);
            PH[qq][s] = hh2;
            PL[qq][s] = ll2;
        }
    }
    __syncthreads();

    // ---- PV (frag-ordered ktn); write c in FA (KF=8) ----
    const int gbase = s_lo >> 4;
    for (int ht = wp; ht < 16; ht += 4) {
        f32x4 acc = {};
        const unsigned short* ktb = ktn + ((size_t)(b * 16 + ht) * 126) * 256;
#pragma unroll
        for (int sc = 0; sc < 5; ++sc) {
            const bf16x8 ph = *(const bf16x8*)((const char*)&PH[srow + lq][0] + sc * 64 + lk * 16);
            const bf16x8 pl = *(const bf16x8*)((const char*)&PL[srow + lq][0] + sc * 64 + lk * 16);
            const bf16x8 bt = *(const bf16x8*)(
                ktb + (size_t)(gbase + 2 * sc + (lk >> 1)) * 256 + (lk & 1) * 128 + lq * 8);
            acc = __builtin_amdgcn_mfma_f32_16x16x32_bf16(ph, bt, acc, 0, 0, 0);
            acc = __builtin_amdgcn_mfma_f32_16x16x32_bf16(pl, bt, acc, 0, 0, 0);
        }
        const int rt_c = b * 125 + ((t0 + srow) >> 4);
        const size_t base = (((size_t)rt_c * 8 + (ht >> 1)) * 4 +
                             ((ht & 1) * 2 + (lq >> 3))) * 16;
#pragma unroll
        for (int r = 0; r < 4; ++r) {
            const int trow = t0 + srow + lk * 4 + r;
            if (trow < T_) {
                unsigned short hh2, ll2;
                split1(acc[r], hh2, ll2);
                const size_t o = (base + (lk * 4 + r)) * 8 + (lq & 7);
                Ch[o] = hh2;
                Cl[o] = ll2;
            }
        }
    }
}

// ---------------------------------------------------------------------------
// gemm_fused v2: 32-row blocks (grid 500), 512 thr / 8 waves. Wave w owns
// row-subtile rts=w&1 (rt = bid*2+rts) x col-tiles wp=w>>1 + i*4. B-frags
// depend only on (ct,kf): the rts=0/1 wave pairs read IDENTICAL B addresses
// (L1 reuse) -> total L2 B-traffic halves vs R18. enh passes through 32KB
// swizzled LDS. Per-wave arithmetic & K-order identical to R18.
__global__ __launch_bounds__(512) void gemm_fused(
    const unsigned short* __restrict__ ch, const unsigned short* __restrict__ cl,
    const unsigned short* __restrict__ qh, const unsigned short* __restrict__ ql,
    const unsigned short* __restrict__ wenh, const unsigned short* __restrict__ wenl,
    const float* __restrict__ b_enh,
    const unsigned short* __restrict__ wmnh, const unsigned short* __restrict__ wmnl,
    const float* __restrict__ b_mask, float* __restrict__ out)
{
    __shared__ unsigned short EH[32 * 256];
    __shared__ unsigned short EL[32 * 256];

    const int tid = threadIdx.x;
    const int w = tid >> 6, l = tid & 63;
    const int rts = w & 1, wp = w >> 1;
    const int lq = l & 15, lk = l >> 4;
    const int rt = blockIdx.x * 2 + rts;

    // ---- phase 1: enh rows rt*16..+15, acc[i] = col-tile wp + i*4 ----
    f32x4 acc[4] = {};
#pragma unroll
    for (int ph = 0; ph < 2; ++ph) {
        const unsigned short* Ah = ph ? qh : ch;
        const unsigned short* Al = ph ? ql : cl;
        bf16x8 aH[8], aL[8];
#pragma unroll
        for (int kf = 0; kf < 8; ++kf) {
            const size_t ob = ((size_t)(rt * 8 + kf)) * 1024 + (size_t)l * 16;
            aH[kf] = *(const bf16x8*)((const char*)Ah + ob);
            aL[kf] = *(const bf16x8*)((const char*)Al + ob);
        }
#pragma unroll
        for (int i = 0; i < 4; ++i) {
            const int ct = wp + i * 4;
#pragma unroll
            for (int kf = 0; kf < 8; ++kf) {
                const size_t bo = ((size_t)(ct * 16 + ph * 8 + kf)) * 1024 + (size_t)l * 16;
                const bf16x8 bh = *(const bf16x8*)((const char*)wenh + bo);
                const bf16x8 bl = *(const bf16x8*)((const char*)wenl + bo);
                acc[i] = __builtin_amdgcn_mfma_f32_16x16x32_bf16(aH[kf], bh, acc[i], 0, 0, 0);
                acc[i] = __builtin_amdgcn_mfma_f32_16x16x32_bf16(aH[kf], bl, acc[i], 0, 0, 0);
                acc[i] = __builtin_amdgcn_mfma_f32_16x16x32_bf16(aL[kf], bh, acc[i], 0, 0, 0);
            }
        }
    }

    // ---- enh -> LDS (split, swizzled; row = rts*16 + lk*4+r, col=ct*16+lq) ----
#pragma unroll
    for (int i = 0; i < 4; ++i) {
        const int ct = wp + i * 4;
        const int col = ct * 16 + lq;
        const float bv = b_enh[col];
#pragma unroll
        for (int r = 0; r < 4; ++r) {
            const int row = rts * 16 + lk * 4 + r;
            unsigned short h2, l2;
            split1(tanhf(acc[i][r] + bv), h2, l2);
            unsigned off = (unsigned)(row * 512 + col * 2);
            off ^= (unsigned)((row & 7) << 4);
            *(unsigned short*)((char*)EH + off) = h2;
            *(unsigned short*)((char*)EL + off) = l2;
        }
    }
    __syncthreads();

    // ---- phase 2: out = sigmoid(enh @ Wm^T + bm); A-frags from LDS own sub ----
    bf16x8 aH[8], aL[8];
#pragma unroll
    for (int kf = 0; kf < 8; ++kf) {
        const int t = rts * 16 + lq;
        unsigned off = (unsigned)(t * 512 + kf * 64 + lk * 16);
        off ^= (unsigned)((t & 7) << 4);
        aH[kf] = *(const bf16x8*)((const char*)EH + off);
        aL[kf] = *(const bf16x8*)((const char*)EL + off);
    }
#pragma unroll
    for (int i = 0; i < 5; ++i) {
        const int ct = wp + i * 4;
        if (ct <= 16) {
            f32x4 o = {};
#pragma unroll
            for (int kf = 0; kf < 8; ++kf) {
                const size_t bo = ((size_t)(ct * 8 + kf)) * 1024 + (size_t)l * 16;
                const bf16x8 bh = *(const bf16x8*)((const char*)wmnh + bo);
                const bf16x8 bl = *(const bf16x8*)((const char*)wmnl + bo);
                o = __builtin_amdgcn_mfma_f32_16x16x32_bf16(aH[kf], bh, o, 0, 0, 0);
                o = __builtin_amdgcn_mfma_f32_16x16x32_bf16(aH[kf], bl, o, 0, 0, 0);
                o = __builtin_amdgcn_mfma_f32_16x16x32_bf16(aL[kf], bh, o, 0, 0, 0);
            }
            const int col = ct * 16 + lq;
            if (col < FOUT_) {
                const float bv = b_mask[col];
#pragma unroll
                for (int r = 0; r < 4; ++r) {
                    const int row = rt * 16 + lk * 4 + r;
                    out[(size_t)row * FOUT_ + col] = 1.f / (1.f + expf(-(o[r] + bv)));
                }
            }
        }
    }
}

// ---------------------------------------------------------------------------
extern "C" void kernel_launch(void* const* d_in, const int* in_sizes, int n_in,
                              void* d_out, int out_size, void* d_ws, size_t ws_size,
                              hipStream_t stream)
{
    const float* k       = (const float*)d_in[0];
    const float* q       = (const float*)d_in[1];
    const float* W_score = (const float*)d_in[2];
    const float* W_enh   = (const float*)d_in[3];
    const float* b_enh   = (const float*)d_in[4];
    const float* W_mask  = (const float*)d_in[5];
    const float* b_mask  = (const float*)d_in[6];
    float* out = (float*)d_out;

    const size_t MH = (size_t)B_ * T_ * H_;          // 4.096M elems
    unsigned short* q2h = (unsigned short*)d_ws;
    unsigned short* q2l = q2h + MH;
    unsigned short* ch  = q2l + MH;
    unsigned short* cl  = ch + MH;
    unsigned short* kfh = cl + MH;
    unsigned short* kfl = kfh + MH;
    unsigned short* ktn = kfl + MH;                  // 8*16*126*256
    unsigned short* wsnh = ktn + (size_t)B_ * 16 * 126 * 256;
    unsigned short* wsnl = wsnh + 65536;
    unsigned short* wenh = wsnl + 65536;
    unsigned short* wenl = wenh + 131072;
    unsigned short* wmnh = wenl + 131072;            // 320x256 FA
    unsigned short* wmnl = wmnh + 81920;

    dim3 blk(256);

    prep<<<dim3(4288), blk, 0, stream>>>(
        k, q, W_score, W_enh, W_mask,
        q2h, q2l, kfh, kfl, ktn, wsnh, wsnl, wenh, wenl, wmnh, wmnl);

    band_attn_mfma<<<dim3(504), dim3(512), 0, stream>>>(
        q2h, q2l, wsnh, wsnl, kfh, kfl, ktn, ch, cl);

    gemm_fused<<<dim3(500), dim3(512), 0, stream>>>(
        ch, cl, q2h, q2l, wenh, wenl, b_enh, wmnh, wmnl, b_mask, out);
}